// Round 1
// baseline (11904.330 us; speedup 1.0000x reference)
//
#include <hip/hip_runtime.h>
#include <hip/hip_bf16.h>
#include <math.h>

// Problem constants (also derived from in_sizes at launch for safety)
#define FDIM 256
#define CDIM 40
#define ALPHA_F 0.5f

static inline int cdiv(int a, int b) { return (a + b - 1) / b; }

// ---------------- degree counting ----------------
__global__ __launch_bounds__(256) void k_degrees(const int* __restrict__ row,
                                                 const int* __restrict__ col,
                                                 float* __restrict__ deg_out,
                                                 float* __restrict__ deg_in, int E) {
    int e = blockIdx.x * 256 + threadIdx.x;
    if (e < E) {
        atomicAdd(&deg_out[row[e]], 1.0f);
        atomicAdd(&deg_in[col[e]], 1.0f);
    }
}

// in-place deg -> (deg>0 ? rsqrt(deg) : 0)
__global__ __launch_bounds__(256) void k_invsqrt(float* __restrict__ deg, int n) {
    int i = blockIdx.x * 256 + threadIdx.x;
    if (i < n) {
        float d = deg[i];
        deg[i] = d > 0.0f ? rsqrtf(d) : 0.0f;
    }
}

__global__ __launch_bounds__(256) void k_edgew(const int* __restrict__ row,
                                               const int* __restrict__ col,
                                               const float* __restrict__ inv_out,
                                               const float* __restrict__ inv_in,
                                               float* __restrict__ ew, int E) {
    int e = blockIdx.x * 256 + threadIdx.x;
    if (e < E) ew[e] = inv_out[row[e]] * inv_in[col[e]];
}

// ---------------- scatter over 256 features (both directions) ----------------
// 4 edges per 256-thread block; 64 lanes cover 256 floats as float4.
__global__ __launch_bounds__(256) void k_scatter256(const float* __restrict__ h,
                                                    const int* __restrict__ row,
                                                    const int* __restrict__ col,
                                                    const float* __restrict__ ew,
                                                    float* __restrict__ agg,
                                                    float* __restrict__ aggt, int E) {
    int sub = threadIdx.x >> 6;
    int lane = threadIdx.x & 63;
    int e = blockIdx.x * 4 + sub;
    if (e >= E) return;
    int r = row[e], c = col[e];
    float w = ew[e];
    float4 vc = ((const float4*)(h + (size_t)c * FDIM))[lane];
    float4 vr = ((const float4*)(h + (size_t)r * FDIM))[lane];
    float* ar = agg + (size_t)r * FDIM + lane * 4;
    float* atc = aggt + (size_t)c * FDIM + lane * 4;
    atomicAdd(ar + 0, w * vc.x);
    atomicAdd(ar + 1, w * vc.y);
    atomicAdd(ar + 2, w * vc.z);
    atomicAdd(ar + 3, w * vc.w);
    atomicAdd(atc + 0, w * vr.x);
    atomicAdd(atc + 1, w * vr.y);
    atomicAdd(atc + 2, w * vr.z);
    atomicAdd(atc + 3, w * vr.w);
}

// ---------------- fused dual GEMM ----------------
// mode 0: out = relu(A*(A@Ws.T + bs) + (1-A)*(At@Wd.T + bd))
// mode 1: same, no relu
// mode 2: out = A@Ws.T ; outD = At@Wd.T   (no bias, no mix)
#define BM 64
#define BN 64
#define BK 16
__global__ __launch_bounds__(256) void k_gemm_dual(const float* __restrict__ A,
                                                   const float* __restrict__ At,
                                                   const float* __restrict__ Ws,
                                                   const float* __restrict__ Wd,
                                                   const float* __restrict__ bs,
                                                   const float* __restrict__ bd,
                                                   float* __restrict__ out,
                                                   float* __restrict__ outD,
                                                   int Nn, int K, int J, int mode) {
    __shared__ float sA[BM][BK + 1];
    __shared__ float sAt[BM][BK + 1];
    __shared__ float sBs[BK][BN + 1];
    __shared__ float sBd[BK][BN + 1];

    int tid = threadIdx.x;
    int tx = tid % 16, ty = tid / 16;
    int n0 = blockIdx.x * BM;
    int j0 = blockIdx.y * BN;

    float accS[4][4] = {};
    float accD[4][4] = {};

    for (int k0 = 0; k0 < K; k0 += BK) {
        for (int i = tid; i < BM * BK; i += 256) {
            int r = i / BK, c = i % BK;
            int n = n0 + r;
            float a = 0.f, at = 0.f;
            if (n < Nn) {
                a = A[(size_t)n * K + k0 + c];
                at = At[(size_t)n * K + k0 + c];
            }
            sA[r][c] = a;
            sAt[r][c] = at;
        }
        for (int i = tid; i < BK * BN; i += 256) {
            int j = i / BK, c = i % BK;
            int jj = j0 + j;
            float wsv = 0.f, wdv = 0.f;
            if (jj < J) {
                wsv = Ws[(size_t)jj * K + k0 + c];
                wdv = Wd[(size_t)jj * K + k0 + c];
            }
            sBs[c][j] = wsv;
            sBd[c][j] = wdv;
        }
        __syncthreads();
#pragma unroll
        for (int kk = 0; kk < BK; ++kk) {
            float av[4], atv[4], bsv[4], bdv[4];
#pragma unroll
            for (int i = 0; i < 4; ++i) {
                av[i] = sA[ty * 4 + i][kk];
                atv[i] = sAt[ty * 4 + i][kk];
            }
#pragma unroll
            for (int j = 0; j < 4; ++j) {
                bsv[j] = sBs[kk][tx * 4 + j];
                bdv[j] = sBd[kk][tx * 4 + j];
            }
#pragma unroll
            for (int i = 0; i < 4; ++i)
#pragma unroll
                for (int j = 0; j < 4; ++j) {
                    accS[i][j] += av[i] * bsv[j];
                    accD[i][j] += atv[i] * bdv[j];
                }
        }
        __syncthreads();
    }

    for (int i = 0; i < 4; ++i) {
        int n = n0 + ty * 4 + i;
        if (n >= Nn) continue;
        for (int j = 0; j < 4; ++j) {
            int jj = j0 + tx * 4 + j;
            if (jj >= J) continue;
            if (mode == 2) {
                out[(size_t)n * J + jj] = accS[i][j];
                outD[(size_t)n * J + jj] = accD[i][j];
            } else {
                float v = ALPHA_F * (accS[i][j] + bs[jj]) + (1.0f - ALPHA_F) * (accD[i][j] + bd[jj]);
                if (mode == 0) v = fmaxf(v, 0.0f);
                out[(size_t)n * J + jj] = v;
            }
        }
    }
}

// ---------------- layer-3 scatter over 40 classes ----------------
__global__ __launch_bounds__(256) void k_scatter40(const float* __restrict__ zs,
                                                   const float* __restrict__ zd,
                                                   const int* __restrict__ row,
                                                   const int* __restrict__ col,
                                                   const float* __restrict__ ew,
                                                   float* __restrict__ out, int E) {
    int idx = blockIdx.x * 256 + threadIdx.x;
    if (idx >= E * CDIM) return;
    int e = idx / CDIM;
    int cf = idx % CDIM;
    int r = row[e], c = col[e];
    float w = ew[e];
    atomicAdd(&out[(size_t)r * CDIM + cf], ALPHA_F * w * zs[(size_t)c * CDIM + cf]);
    atomicAdd(&out[(size_t)c * CDIM + cf], (1.0f - ALPHA_F) * w * zd[(size_t)r * CDIM + cf]);
}

// ---------------- bias + log_softmax in-place, one wave per row ----------------
__global__ __launch_bounds__(256) void k_logsoftmax(float* __restrict__ out,
                                                    const float* __restrict__ bs,
                                                    const float* __restrict__ bd, int Nn) {
    int wave = threadIdx.x >> 6;
    int lane = threadIdx.x & 63;
    int n = blockIdx.x * 4 + wave;
    if (n >= Nn) return;
    float val = 0.0f;
    float v = -INFINITY;
    if (lane < CDIM) {
        val = out[(size_t)n * CDIM + lane] + ALPHA_F * bs[lane] + (1.0f - ALPHA_F) * bd[lane];
        v = val;
    }
    for (int off = 32; off; off >>= 1) v = fmaxf(v, __shfl_xor(v, off));
    float ex = (lane < CDIM) ? expf(val - v) : 0.0f;
    for (int off = 32; off; off >>= 1) ex += __shfl_xor(ex, off);
    float lse = logf(ex);
    // ex now holds the full sum in every lane (butterfly), recompute own term:
    if (lane < CDIM) out[(size_t)n * CDIM + lane] = val - v - lse;
}

extern "C" void kernel_launch(void* const* d_in, const int* in_sizes, int n_in,
                              void* d_out, int out_size, void* d_ws, size_t ws_size,
                              hipStream_t stream) {
    const int N = in_sizes[0] / FDIM;
    const int E = in_sizes[1] / 2;

    const float* x = (const float*)d_in[0];
    const int* ei = (const int*)d_in[1];
    const int* row = ei;
    const int* col = ei + E;
    const float* ws1 = (const float*)d_in[2];
    const float* bs1 = (const float*)d_in[3];
    const float* wd1 = (const float*)d_in[4];
    const float* bd1 = (const float*)d_in[5];
    const float* ws2 = (const float*)d_in[6];
    const float* bs2 = (const float*)d_in[7];
    const float* wd2 = (const float*)d_in[8];
    const float* bd2 = (const float*)d_in[9];
    const float* ws3 = (const float*)d_in[10];
    const float* bs3 = (const float*)d_in[11];
    const float* wd3 = (const float*)d_in[12];
    const float* bd3 = (const float*)d_in[13];
    float* out = (float*)d_out;

    float* wsf = (float*)d_ws;
    float* ew = wsf;                       // E
    float* deg = wsf + E;                  // 2N (deg_out | deg_in)
    float* h = deg + 2 * (size_t)N;        // N*FDIM
    float* agg = h + (size_t)N * FDIM;     // N*FDIM
    float* aggt = agg + (size_t)N * FDIM;  // N*FDIM

    // edge weights
    hipMemsetAsync(deg, 0, sizeof(float) * 2 * (size_t)N, stream);
    k_degrees<<<cdiv(E, 256), 256, 0, stream>>>(row, col, deg, deg + N, E);
    k_invsqrt<<<cdiv(2 * N, 256), 256, 0, stream>>>(deg, 2 * N);
    k_edgew<<<cdiv(E, 256), 256, 0, stream>>>(row, col, deg, deg + N, ew, E);

    dim3 gemm_grid(cdiv(N, BM), FDIM / BN);

    // layer 1
    hipMemsetAsync(agg, 0, sizeof(float) * 2 * (size_t)N * FDIM, stream);
    k_scatter256<<<cdiv(E, 4), 256, 0, stream>>>(x, row, col, ew, agg, aggt, E);
    k_gemm_dual<<<gemm_grid, 256, 0, stream>>>(agg, aggt, ws1, wd1, bs1, bd1, h, nullptr, N, FDIM, FDIM, 0);

    // layer 2
    hipMemsetAsync(agg, 0, sizeof(float) * 2 * (size_t)N * FDIM, stream);
    k_scatter256<<<cdiv(E, 4), 256, 0, stream>>>(h, row, col, ew, agg, aggt, E);
    k_gemm_dual<<<gemm_grid, 256, 0, stream>>>(agg, aggt, ws2, wd2, bs2, bd2, h, nullptr, N, FDIM, FDIM, 0);

    // layer 3: GEMM first (commutes with segment_sum), then scatter over C=40
    dim3 gemm3_grid(cdiv(N, BM), 1);
    k_gemm_dual<<<gemm3_grid, 256, 0, stream>>>(h, h, ws3, wd3, nullptr, nullptr, agg /*zs*/, aggt /*zd*/, N, FDIM, CDIM, 2);
    hipMemsetAsync(out, 0, sizeof(float) * (size_t)N * CDIM, stream);
    k_scatter40<<<cdiv(E * CDIM, 256), 256, 0, stream>>>(agg, aggt, row, col, ew, out, E);
    k_logsoftmax<<<cdiv(N, 4), 256, 0, stream>>>(out, bs3, bd3, N);
}

// Round 2
// 1687.960 us; speedup vs baseline: 7.0525x; 7.0525x over previous
//
#include <hip/hip_runtime.h>
#include <math.h>

#define FDIM 256
#define CDIM 40
#define ALPHA_F 0.5f

static inline int cdiv(int a, int b) { return (a + b - 1) / b; }

// ---------------- degree counting (int) ----------------
__global__ __launch_bounds__(256) void k_count(const int* __restrict__ row,
                                               const int* __restrict__ col,
                                               int* __restrict__ cnt_r,
                                               int* __restrict__ cnt_c, int E) {
    int e = blockIdx.x * 256 + threadIdx.x;
    if (e < E) {
        atomicAdd(&cnt_r[row[e]], 1);
        atomicAdd(&cnt_c[col[e]], 1);
    }
}

// inv[i] = cnt>0 ? rsqrt(cnt) : 0   (cnt_r|cnt_c contiguous, inv_out|inv_in contiguous)
__global__ __launch_bounds__(256) void k_inv(const int* __restrict__ cnt,
                                             float* __restrict__ inv, int n) {
    int i = blockIdx.x * 256 + threadIdx.x;
    if (i < n) {
        int c = cnt[i];
        inv[i] = c > 0 ? rsqrtf((float)c) : 0.0f;
    }
}

// ---------------- 2-level exclusive scan (N <= 256*256) ----------------
__global__ __launch_bounds__(256) void k_scan1(const int* __restrict__ cnt,
                                               int* __restrict__ ptr,
                                               int* __restrict__ bsum, int n) {
    __shared__ int s[256];
    int t = threadIdx.x;
    int i = blockIdx.x * 256 + t;
    int v = (i < n) ? cnt[i] : 0;
    s[t] = v;
    __syncthreads();
    for (int off = 1; off < 256; off <<= 1) {
        int u = (t >= off) ? s[t - off] : 0;
        __syncthreads();
        s[t] += u;
        __syncthreads();
    }
    if (i < n) ptr[i] = s[t] - v;  // exclusive within block
    if (t == 255) bsum[blockIdx.x] = s[255];
}

__global__ __launch_bounds__(256) void k_scan2(int* __restrict__ bsum, int nb) {
    __shared__ int s[256];
    int t = threadIdx.x;
    int v = (t < nb) ? bsum[t] : 0;
    s[t] = v;
    __syncthreads();
    for (int off = 1; off < 256; off <<= 1) {
        int u = (t >= off) ? s[t - off] : 0;
        __syncthreads();
        s[t] += u;
        __syncthreads();
    }
    if (t < nb) bsum[t] = s[t] - v;  // exclusive block offsets
}

__global__ __launch_bounds__(256) void k_scan3(int* __restrict__ ptr,
                                               const int* __restrict__ bsum,
                                               int n, int total) {
    int i = blockIdx.x * 256 + threadIdx.x;
    if (i < n) ptr[i] += bsum[blockIdx.x];
    if (blockIdx.x == 0 && threadIdx.x == 0) ptr[n] = total;
}

// ---------------- fill CSR (by row) and CSC (by col) ----------------
__global__ __launch_bounds__(256) void k_fill(const int* __restrict__ row,
                                              const int* __restrict__ col,
                                              const float* __restrict__ inv_out,
                                              const float* __restrict__ inv_in,
                                              const int* __restrict__ rptr,
                                              const int* __restrict__ cptr,
                                              int* __restrict__ fr, int* __restrict__ fc,
                                              int* __restrict__ nbr_r, float* __restrict__ w_r,
                                              int* __restrict__ nbr_c, float* __restrict__ w_c,
                                              int E) {
    int e = blockIdx.x * 256 + threadIdx.x;
    if (e >= E) return;
    int r = row[e], c = col[e];
    float wv = inv_out[r] * inv_in[c];
    int p = rptr[r] + atomicAdd(&fr[r], 1);
    nbr_r[p] = c;
    w_r[p] = wv;
    int q = cptr[c] + atomicAdd(&fc[c], 1);
    nbr_c[q] = r;
    w_c[q] = wv;
}

// ---------------- gather aggregation over 256 features ----------------
// blockIdx.y = 0: agg[n] = sum_{CSR} w*h[col] ; blockIdx.y = 1: aggt[n] = sum_{CSC} w*h[row]
__global__ __launch_bounds__(256) void k_gather256(const float* __restrict__ h,
                                                   const int* __restrict__ rptr,
                                                   const int* __restrict__ nbr_r,
                                                   const float* __restrict__ w_r,
                                                   const int* __restrict__ cptr,
                                                   const int* __restrict__ nbr_c,
                                                   const float* __restrict__ w_c,
                                                   float* __restrict__ agg,
                                                   float* __restrict__ aggt, int N) {
    int wv = threadIdx.x >> 6, lane = threadIdx.x & 63;
    int n = blockIdx.x * 4 + wv;
    if (n >= N) return;
    const int* ptr;
    const int* nbr;
    const float* w;
    float* out;
    if (blockIdx.y == 0) { ptr = rptr; nbr = nbr_r; w = w_r; out = agg; }
    else                 { ptr = cptr; nbr = nbr_c; w = w_c; out = aggt; }
    int s = ptr[n], t = ptr[n + 1];
    float4 acc = {0.f, 0.f, 0.f, 0.f};
    int p = s;
    for (; p + 1 < t; p += 2) {
        int c0 = nbr[p], c1 = nbr[p + 1];
        float w0 = w[p], w1 = w[p + 1];
        float4 v0 = ((const float4*)(h + (size_t)c0 * FDIM))[lane];
        float4 v1 = ((const float4*)(h + (size_t)c1 * FDIM))[lane];
        acc.x += w0 * v0.x + w1 * v1.x;
        acc.y += w0 * v0.y + w1 * v1.y;
        acc.z += w0 * v0.z + w1 * v1.z;
        acc.w += w0 * v0.w + w1 * v1.w;
    }
    if (p < t) {
        int c0 = nbr[p];
        float w0 = w[p];
        float4 v0 = ((const float4*)(h + (size_t)c0 * FDIM))[lane];
        acc.x += w0 * v0.x;
        acc.y += w0 * v0.y;
        acc.z += w0 * v0.z;
        acc.w += w0 * v0.w;
    }
    ((float4*)(out + (size_t)n * FDIM))[lane] = acc;
}

// ---------------- fused dual GEMM ----------------
// mode 0: out = relu(A*(A@Ws.T+bs) + (1-A)*(At@Wd.T+bd)) ; mode 2: out=A@Ws.T, outD=At@Wd.T
#define BM 64
#define BN 64
#define BK 16
__global__ __launch_bounds__(256) void k_gemm_dual(const float* __restrict__ A,
                                                   const float* __restrict__ At,
                                                   const float* __restrict__ Ws,
                                                   const float* __restrict__ Wd,
                                                   const float* __restrict__ bs,
                                                   const float* __restrict__ bd,
                                                   float* __restrict__ out,
                                                   float* __restrict__ outD,
                                                   int Nn, int K, int J, int mode) {
    __shared__ float sA[BM][BK + 1];
    __shared__ float sAt[BM][BK + 1];
    __shared__ float sBs[BK][BN + 1];
    __shared__ float sBd[BK][BN + 1];

    int tid = threadIdx.x;
    int tx = tid % 16, ty = tid / 16;
    int n0 = blockIdx.x * BM;
    int j0 = blockIdx.y * BN;

    float accS[4][4] = {};
    float accD[4][4] = {};

    for (int k0 = 0; k0 < K; k0 += BK) {
        for (int i = tid; i < BM * BK; i += 256) {
            int r = i / BK, c = i % BK;
            int n = n0 + r;
            float a = 0.f, at = 0.f;
            if (n < Nn) {
                a = A[(size_t)n * K + k0 + c];
                at = At[(size_t)n * K + k0 + c];
            }
            sA[r][c] = a;
            sAt[r][c] = at;
        }
        for (int i = tid; i < BK * BN; i += 256) {
            int j = i / BK, c = i % BK;
            int jj = j0 + j;
            float wsv = 0.f, wdv = 0.f;
            if (jj < J) {
                wsv = Ws[(size_t)jj * K + k0 + c];
                wdv = Wd[(size_t)jj * K + k0 + c];
            }
            sBs[c][j] = wsv;
            sBd[c][j] = wdv;
        }
        __syncthreads();
#pragma unroll
        for (int kk = 0; kk < BK; ++kk) {
            float av[4], atv[4], bsv[4], bdv[4];
#pragma unroll
            for (int i = 0; i < 4; ++i) {
                av[i] = sA[ty * 4 + i][kk];
                atv[i] = sAt[ty * 4 + i][kk];
            }
#pragma unroll
            for (int j = 0; j < 4; ++j) {
                bsv[j] = sBs[kk][tx * 4 + j];
                bdv[j] = sBd[kk][tx * 4 + j];
            }
#pragma unroll
            for (int i = 0; i < 4; ++i)
#pragma unroll
                for (int j = 0; j < 4; ++j) {
                    accS[i][j] += av[i] * bsv[j];
                    accD[i][j] += atv[i] * bdv[j];
                }
        }
        __syncthreads();
    }

    for (int i = 0; i < 4; ++i) {
        int n = n0 + ty * 4 + i;
        if (n >= Nn) continue;
        for (int j = 0; j < 4; ++j) {
            int jj = j0 + tx * 4 + j;
            if (jj >= J) continue;
            if (mode == 2) {
                out[(size_t)n * J + jj] = accS[i][j];
                outD[(size_t)n * J + jj] = accD[i][j];
            } else {
                float v = ALPHA_F * (accS[i][j] + bs[jj]) + (1.0f - ALPHA_F) * (accD[i][j] + bd[jj]);
                if (mode == 0) v = fmaxf(v, 0.0f);
                out[(size_t)n * J + jj] = v;
            }
        }
    }
}

// ---------------- layer 3: gather over 40 classes + bias + log_softmax ----------------
__global__ __launch_bounds__(256) void k_l3(const float* __restrict__ zs,
                                            const float* __restrict__ zd,
                                            const int* __restrict__ rptr,
                                            const int* __restrict__ nbr_r,
                                            const float* __restrict__ w_r,
                                            const int* __restrict__ cptr,
                                            const int* __restrict__ nbr_c,
                                            const float* __restrict__ w_c,
                                            const float* __restrict__ bs,
                                            const float* __restrict__ bd,
                                            float* __restrict__ out, int N) {
    int wv = threadIdx.x >> 6, lane = threadIdx.x & 63;
    int n = blockIdx.x * 4 + wv;
    if (n >= N) return;
    float val = 0.0f;
    if (lane < CDIM) val = ALPHA_F * bs[lane] + (1.0f - ALPHA_F) * bd[lane];
    int s = rptr[n], t = rptr[n + 1];
    for (int p = s; p < t; ++p) {
        int c = nbr_r[p];
        float wt = w_r[p];
        if (lane < CDIM) val += ALPHA_F * wt * zs[(size_t)c * CDIM + lane];
    }
    s = cptr[n];
    t = cptr[n + 1];
    for (int p = s; p < t; ++p) {
        int r = nbr_c[p];
        float wt = w_c[p];
        if (lane < CDIM) val += (1.0f - ALPHA_F) * wt * zd[(size_t)r * CDIM + lane];
    }
    float m = (lane < CDIM) ? val : -INFINITY;
    for (int off = 32; off; off >>= 1) m = fmaxf(m, __shfl_xor(m, off));
    float ex = (lane < CDIM) ? expf(val - m) : 0.0f;
    for (int off = 32; off; off >>= 1) ex += __shfl_xor(ex, off);
    float lse = logf(ex);
    if (lane < CDIM) out[(size_t)n * CDIM + lane] = val - m - lse;
}

extern "C" void kernel_launch(void* const* d_in, const int* in_sizes, int n_in,
                              void* d_out, int out_size, void* d_ws, size_t ws_size,
                              hipStream_t stream) {
    const int N = in_sizes[0] / FDIM;
    const int E = in_sizes[1] / 2;

    const float* x = (const float*)d_in[0];
    const int* ei = (const int*)d_in[1];
    const int* row = ei;
    const int* col = ei + E;
    const float* ws1 = (const float*)d_in[2];
    const float* bs1 = (const float*)d_in[3];
    const float* wd1 = (const float*)d_in[4];
    const float* bd1 = (const float*)d_in[5];
    const float* ws2 = (const float*)d_in[6];
    const float* bs2 = (const float*)d_in[7];
    const float* wd2 = (const float*)d_in[8];
    const float* bd2 = (const float*)d_in[9];
    const float* ws3 = (const float*)d_in[10];
    const float* bs3 = (const float*)d_in[11];
    const float* wd3 = (const float*)d_in[12];
    const float* bd3 = (const float*)d_in[13];
    float* out = (float*)d_out;

    // ---- workspace carve ----
    char* base = (char*)d_ws;
    float* inv_out = (float*)base;             base += sizeof(float) * N;
    float* inv_in = (float*)base;              base += sizeof(float) * N;
    int* cnt_r = (int*)base;                   base += sizeof(int) * N;   // cnt_r|cnt_c|fr|fc contiguous
    int* cnt_c = (int*)base;                   base += sizeof(int) * N;
    int* fr = (int*)base;                      base += sizeof(int) * N;
    int* fc = (int*)base;                      base += sizeof(int) * N;
    int* rptr = (int*)base;                    base += sizeof(int) * (N + 1);
    int* cptr = (int*)base;                    base += sizeof(int) * (N + 1);
    int* bsum = (int*)base;                    base += sizeof(int) * 256;
    int* nbr_r = (int*)base;                   base += sizeof(int) * E;
    float* w_r = (float*)base;                 base += sizeof(float) * E;
    int* nbr_c = (int*)base;                   base += sizeof(int) * E;
    float* w_c = (float*)base;                 base += sizeof(float) * E;
    // 16-byte align the big float4 buffers
    base = (char*)(((size_t)base + 15) & ~(size_t)15);
    float* h = (float*)base;                   base += sizeof(float) * (size_t)N * FDIM;
    float* agg = (float*)base;                 base += sizeof(float) * (size_t)N * FDIM;
    float* aggt = (float*)base;                base += sizeof(float) * (size_t)N * FDIM;

    const int nb = cdiv(N, 256);

    // ---- build normalization + CSR/CSC ----
    hipMemsetAsync(cnt_r, 0, sizeof(int) * 4 * (size_t)N, stream);  // cnt_r,cnt_c,fr,fc
    k_count<<<cdiv(E, 256), 256, 0, stream>>>(row, col, cnt_r, cnt_c, E);
    k_inv<<<cdiv(2 * N, 256), 256, 0, stream>>>(cnt_r, inv_out, 2 * N);  // contiguous pairs
    k_scan1<<<nb, 256, 0, stream>>>(cnt_r, rptr, bsum, N);
    k_scan2<<<1, 256, 0, stream>>>(bsum, nb);
    k_scan3<<<nb, 256, 0, stream>>>(rptr, bsum, N, E);
    k_scan1<<<nb, 256, 0, stream>>>(cnt_c, cptr, bsum, N);
    k_scan2<<<1, 256, 0, stream>>>(bsum, nb);
    k_scan3<<<nb, 256, 0, stream>>>(cptr, bsum, N, E);
    k_fill<<<cdiv(E, 256), 256, 0, stream>>>(row, col, inv_out, inv_in, rptr, cptr,
                                             fr, fc, nbr_r, w_r, nbr_c, w_c, E);

    dim3 ggrid(cdiv(N, 4), 2);
    dim3 gemm_grid(cdiv(N, BM), FDIM / BN);

    // layer 1
    k_gather256<<<ggrid, 256, 0, stream>>>(x, rptr, nbr_r, w_r, cptr, nbr_c, w_c, agg, aggt, N);
    k_gemm_dual<<<gemm_grid, 256, 0, stream>>>(agg, aggt, ws1, wd1, bs1, bd1, h, nullptr, N, FDIM, FDIM, 0);

    // layer 2
    k_gather256<<<ggrid, 256, 0, stream>>>(h, rptr, nbr_r, w_r, cptr, nbr_c, w_c, agg, aggt, N);
    k_gemm_dual<<<gemm_grid, 256, 0, stream>>>(agg, aggt, ws2, wd2, bs2, bd2, h, nullptr, N, FDIM, FDIM, 0);

    // layer 3: GEMM first (commutes with segment_sum), then fused gather+softmax
    dim3 gemm3_grid(cdiv(N, BM), 1);
    k_gemm_dual<<<gemm3_grid, 256, 0, stream>>>(h, h, ws3, wd3, nullptr, nullptr,
                                                agg /*zs*/, aggt /*zd*/, N, FDIM, CDIM, 2);
    k_l3<<<cdiv(N, 4), 256, 0, stream>>>(agg, aggt, rptr, nbr_r, w_r, cptr, nbr_c, w_c,
                                         bs3, bd3, out, N);
}

// Round 3
// 681.622 us; speedup vs baseline: 17.4647x; 2.4764x over previous
//
#include <hip/hip_runtime.h>
#include <math.h>

#define FDIM 256
#define CDIM 40
#define NPAD_TO 128

typedef __attribute__((ext_vector_type(8))) __bf16 bf16x8;
typedef __attribute__((ext_vector_type(4))) float f32x4;

static inline int cdiv(int a, int b) { return (a + b - 1) / b; }

__device__ __forceinline__ float b2f(ushort u) { return __uint_as_float(((unsigned)u) << 16); }
__device__ __forceinline__ ushort f2bf(float f) {
    unsigned u = __float_as_uint(f);
    unsigned r = (u + 0x7FFFu + ((u >> 16) & 1u)) >> 16;
    return (ushort)r;
}

__device__ __forceinline__ void gl_lds16(const void* gsrc, void* ldst) {
    __builtin_amdgcn_global_load_lds((const __attribute__((address_space(1))) unsigned*)gsrc,
                                     (__attribute__((address_space(3))) unsigned*)ldst, 16, 0, 0);
}

// ---------------- degree counting / CSR-CSC build (unchanged from R2) ----------------
__global__ __launch_bounds__(256) void k_count(const int* __restrict__ row,
                                               const int* __restrict__ col,
                                               int* __restrict__ cnt_r,
                                               int* __restrict__ cnt_c, int E) {
    int e = blockIdx.x * 256 + threadIdx.x;
    if (e < E) {
        atomicAdd(&cnt_r[row[e]], 1);
        atomicAdd(&cnt_c[col[e]], 1);
    }
}

__global__ __launch_bounds__(256) void k_inv(const int* __restrict__ cnt,
                                             float* __restrict__ inv, int n) {
    int i = blockIdx.x * 256 + threadIdx.x;
    if (i < n) {
        int c = cnt[i];
        inv[i] = c > 0 ? rsqrtf((float)c) : 0.0f;
    }
}

__global__ __launch_bounds__(256) void k_scan1(const int* __restrict__ cnt,
                                               int* __restrict__ ptr,
                                               int* __restrict__ bsum, int n) {
    __shared__ int s[256];
    int t = threadIdx.x;
    int i = blockIdx.x * 256 + t;
    int v = (i < n) ? cnt[i] : 0;
    s[t] = v;
    __syncthreads();
    for (int off = 1; off < 256; off <<= 1) {
        int u = (t >= off) ? s[t - off] : 0;
        __syncthreads();
        s[t] += u;
        __syncthreads();
    }
    if (i < n) ptr[i] = s[t] - v;
    if (t == 255) bsum[blockIdx.x] = s[255];
}

__global__ __launch_bounds__(256) void k_scan2(int* __restrict__ bsum, int nb) {
    __shared__ int s[256];
    int t = threadIdx.x;
    int v = (t < nb) ? bsum[t] : 0;
    s[t] = v;
    __syncthreads();
    for (int off = 1; off < 256; off <<= 1) {
        int u = (t >= off) ? s[t - off] : 0;
        __syncthreads();
        s[t] += u;
        __syncthreads();
    }
    if (t < nb) bsum[t] = s[t] - v;
}

__global__ __launch_bounds__(256) void k_scan3(int* __restrict__ ptr,
                                               const int* __restrict__ bsum,
                                               int n, int total) {
    int i = blockIdx.x * 256 + threadIdx.x;
    if (i < n) ptr[i] += bsum[blockIdx.x];
    if (blockIdx.x == 0 && threadIdx.x == 0) ptr[n] = total;
}

__global__ __launch_bounds__(256) void k_fill(const int* __restrict__ row,
                                              const int* __restrict__ col,
                                              const float* __restrict__ inv_out,
                                              const float* __restrict__ inv_in,
                                              const int* __restrict__ rptr,
                                              const int* __restrict__ cptr,
                                              int* __restrict__ fr, int* __restrict__ fc,
                                              int* __restrict__ nbr_r, float* __restrict__ w_r,
                                              int* __restrict__ nbr_c, float* __restrict__ w_c,
                                              int E) {
    int e = blockIdx.x * 256 + threadIdx.x;
    if (e >= E) return;
    int r = row[e], c = col[e];
    float wv = inv_out[r] * inv_in[c];
    int p = rptr[r] + atomicAdd(&fr[r], 1);
    nbr_r[p] = c;
    w_r[p] = wv;
    int q = cptr[c] + atomicAdd(&fc[c], 1);
    nbr_c[q] = r;
    w_c[q] = wv;
}

// ---------------- casts ----------------
__global__ __launch_bounds__(256) void k_castx(const float* __restrict__ x,
                                               ushort* __restrict__ xb, int n4) {
    int i = blockIdx.x * 256 + threadIdx.x;
    if (i < n4) {
        float4 v = ((const float4*)x)[i];
        ushort4 o;
        o.x = f2bf(v.x); o.y = f2bf(v.y); o.z = f2bf(v.z); o.w = f2bf(v.w);
        ((ushort4*)xb)[i] = o;
    }
}

// wbuf layout (bf16): w1s[256*256] w1d[256*256] w2s[256*256] w2d[256*256] w3s[64*256] w3d[64*256]
__global__ __launch_bounds__(256) void k_castw(const float* __restrict__ s1, const float* __restrict__ d1,
                                               const float* __restrict__ s2, const float* __restrict__ d2,
                                               const float* __restrict__ s3, const float* __restrict__ d3,
                                               ushort* __restrict__ wb) {
    int i = blockIdx.x * 256 + threadIdx.x;
    const int BIG = 256 * 256;
    const int SM = 64 * 256;
    if (i >= 4 * BIG + 2 * SM) return;
    float v;
    if (i < BIG) v = s1[i];
    else if (i < 2 * BIG) v = d1[i - BIG];
    else if (i < 3 * BIG) v = s2[i - 2 * BIG];
    else if (i < 4 * BIG) v = d2[i - 3 * BIG];
    else {
        int o = i - 4 * BIG;
        const float* src = (o < SM) ? s3 : d3;
        o = (o < SM) ? o : o - SM;
        int r = o >> 8;
        v = (r < CDIM) ? src[(r << 8) + (o & 255)] : 0.0f;
    }
    wb[i] = f2bf(v);
}

// ---------------- bf16 gather (both directions via blockIdx.y) ----------------
__global__ __launch_bounds__(256) void k_gather_bf(const ushort* __restrict__ hb,
                                                   const int* __restrict__ rptr,
                                                   const int* __restrict__ nbr_r,
                                                   const float* __restrict__ w_r,
                                                   const int* __restrict__ cptr,
                                                   const int* __restrict__ nbr_c,
                                                   const float* __restrict__ w_c,
                                                   ushort* __restrict__ agg,
                                                   ushort* __restrict__ aggt, int N) {
    int wv = threadIdx.x >> 6, lane = threadIdx.x & 63;
    int n = blockIdx.x * 4 + wv;
    if (n >= N) return;
    const int* ptr;
    const int* nbr;
    const float* w;
    ushort* out;
    if (blockIdx.y == 0) { ptr = rptr; nbr = nbr_r; w = w_r; out = agg; }
    else                 { ptr = cptr; nbr = nbr_c; w = w_c; out = aggt; }
    int s = ptr[n], t = ptr[n + 1];
    float a0 = 0.f, a1 = 0.f, a2 = 0.f, a3 = 0.f;
    int p = s;
    for (; p + 1 < t; p += 2) {
        int c0 = nbr[p], c1 = nbr[p + 1];
        float w0 = w[p], w1 = w[p + 1];
        ushort4 v0 = ((const ushort4*)(hb + (size_t)c0 * FDIM))[lane];
        ushort4 v1 = ((const ushort4*)(hb + (size_t)c1 * FDIM))[lane];
        a0 += w0 * b2f(v0.x) + w1 * b2f(v1.x);
        a1 += w0 * b2f(v0.y) + w1 * b2f(v1.y);
        a2 += w0 * b2f(v0.z) + w1 * b2f(v1.z);
        a3 += w0 * b2f(v0.w) + w1 * b2f(v1.w);
    }
    if (p < t) {
        int c0 = nbr[p];
        float w0 = w[p];
        ushort4 v0 = ((const ushort4*)(hb + (size_t)c0 * FDIM))[lane];
        a0 += w0 * b2f(v0.x);
        a1 += w0 * b2f(v0.y);
        a2 += w0 * b2f(v0.z);
        a3 += w0 * b2f(v0.w);
    }
    ushort4 o;
    o.x = f2bf(a0); o.y = f2bf(a1); o.z = f2bf(a2); o.w = f2bf(a3);
    ((ushort4*)(out + (size_t)n * FDIM))[lane] = o;
}

// ---------------- MFMA dual GEMM, layers 1-2 ----------------
// out = relu(0.5*(A@Ws^T + bs) + 0.5*(At@Wd^T + bd)), all A/At/W bf16, out bf16.
// Tile: 128 rows x 64 cols, BK=64. LDS 48KB. Swizzle: 16B slot ^= (row&7).
__global__ __launch_bounds__(256) void k_gemm12(const ushort* __restrict__ Ab,
                                                const ushort* __restrict__ Atb,
                                                const ushort* __restrict__ Wsb,
                                                const ushort* __restrict__ Wdb,
                                                const float* __restrict__ bs,
                                                const float* __restrict__ bd,
                                                ushort* __restrict__ outH) {
    __shared__ char smA[16384];
    __shared__ char smAt[16384];
    __shared__ char smWs[8192];
    __shared__ char smWd[8192];

    const int tid = threadIdx.x;
    const int wv = tid >> 6, lane = tid & 63;
    const int n0 = blockIdx.x * 128;
    const int j0 = blockIdx.y * 64;

    const char* Abase = (const char*)Ab;
    const char* Atbase = (const char*)Atb;
    const char* Wsbase = (const char*)Wsb;
    const char* Wdbase = (const char*)Wdb;

    f32x4 accS[2][4] = {};
    f32x4 accD[2][4] = {};

    for (int k0 = 0; k0 < FDIM; k0 += 64) {
        // stage A / At: 1024 slots of 16B each; 4 issues per wave
#pragma unroll
        for (int it = 0; it < 4; ++it) {
            int si = (wv * 4 + it) * 64 + lane;
            int r = si >> 3, sl = si & 7;
            int gs = sl ^ (r & 7);
            size_t goff = (size_t)(n0 + r) * (FDIM * 2) + k0 * 2 + gs * 16;
            gl_lds16(Abase + goff, smA + si * 16);
            gl_lds16(Atbase + goff, smAt + si * 16);
        }
        // stage Ws / Wd: 512 slots; 2 issues per wave
#pragma unroll
        for (int it = 0; it < 2; ++it) {
            int si = (wv * 2 + it) * 64 + lane;
            int r = si >> 3, sl = si & 7;
            int gs = sl ^ (r & 7);
            size_t goff = (size_t)(j0 + r) * (FDIM * 2) + k0 * 2 + gs * 16;
            gl_lds16(Wsbase + goff, smWs + si * 16);
            gl_lds16(Wdbase + goff, smWd + si * 16);
        }
        __syncthreads();
#pragma unroll
        for (int kh = 0; kh < 2; ++kh) {
            bf16x8 aS[2], aT[2], bS[4], bD[4];
#pragma unroll
            for (int mi = 0; mi < 2; ++mi) {
                int r = wv * 32 + mi * 16 + (lane & 15);
                int off = r * 128 + (((kh * 4 + (lane >> 4)) ^ (r & 7)) * 16);
                aS[mi] = *(const bf16x8*)(smA + off);
                aT[mi] = *(const bf16x8*)(smAt + off);
            }
#pragma unroll
            for (int ni = 0; ni < 4; ++ni) {
                int r = ni * 16 + (lane & 15);
                int off = r * 128 + (((kh * 4 + (lane >> 4)) ^ (r & 7)) * 16);
                bS[ni] = *(const bf16x8*)(smWs + off);
                bD[ni] = *(const bf16x8*)(smWd + off);
            }
#pragma unroll
            for (int mi = 0; mi < 2; ++mi)
#pragma unroll
                for (int ni = 0; ni < 4; ++ni) {
                    accS[mi][ni] = __builtin_amdgcn_mfma_f32_16x16x32_bf16(aS[mi], bS[ni], accS[mi][ni], 0, 0, 0);
                    accD[mi][ni] = __builtin_amdgcn_mfma_f32_16x16x32_bf16(aT[mi], bD[ni], accD[mi][ni], 0, 0, 0);
                }
        }
        __syncthreads();
    }

#pragma unroll
    for (int mi = 0; mi < 2; ++mi)
#pragma unroll
        for (int ni = 0; ni < 4; ++ni) {
            int j = j0 + ni * 16 + (lane & 15);
            float bsv = bs[j], bdv = bd[j];
            f32x4 cs = accS[mi][ni], cd = accD[mi][ni];
#pragma unroll
            for (int r = 0; r < 4; ++r) {
                int n = n0 + wv * 32 + mi * 16 + (lane >> 4) * 4 + r;
                float v = 0.5f * (cs[r] + bsv) + 0.5f * (cd[r] + bdv);
                v = fmaxf(v, 0.0f);
                outH[(size_t)n * FDIM + j] = f2bf(v);
            }
        }
}

// ---------------- MFMA layer-3 GEMM: zs = h@Ws^T, zd = h@Wd^T (J=40 padded to 64) ----------------
__global__ __launch_bounds__(256) void k_gemm3(const ushort* __restrict__ Hb,
                                               const ushort* __restrict__ Wsb,
                                               const ushort* __restrict__ Wdb,
                                               float* __restrict__ zs,
                                               float* __restrict__ zd) {
    __shared__ char smA[16384];
    __shared__ char smWs[8192];
    __shared__ char smWd[8192];

    const int tid = threadIdx.x;
    const int wv = tid >> 6, lane = tid & 63;
    const int n0 = blockIdx.x * 128;

    const char* Abase = (const char*)Hb;
    const char* Wsbase = (const char*)Wsb;
    const char* Wdbase = (const char*)Wdb;

    f32x4 accS[2][4] = {};
    f32x4 accD[2][4] = {};

    for (int k0 = 0; k0 < FDIM; k0 += 64) {
#pragma unroll
        for (int it = 0; it < 4; ++it) {
            int si = (wv * 4 + it) * 64 + lane;
            int r = si >> 3, sl = si & 7;
            int gs = sl ^ (r & 7);
            size_t goff = (size_t)(n0 + r) * (FDIM * 2) + k0 * 2 + gs * 16;
            gl_lds16(Abase + goff, smA + si * 16);
        }
#pragma unroll
        for (int it = 0; it < 2; ++it) {
            int si = (wv * 2 + it) * 64 + lane;
            int r = si >> 3, sl = si & 7;
            int gs = sl ^ (r & 7);
            size_t goff = (size_t)r * (FDIM * 2) + k0 * 2 + gs * 16;
            gl_lds16(Wsbase + goff, smWs + si * 16);
            gl_lds16(Wdbase + goff, smWd + si * 16);
        }
        __syncthreads();
#pragma unroll
        for (int kh = 0; kh < 2; ++kh) {
            bf16x8 aS[2], bS[4], bD[4];
#pragma unroll
            for (int mi = 0; mi < 2; ++mi) {
                int r = wv * 32 + mi * 16 + (lane & 15);
                int off = r * 128 + (((kh * 4 + (lane >> 4)) ^ (r & 7)) * 16);
                aS[mi] = *(const bf16x8*)(smA + off);
            }
#pragma unroll
            for (int ni = 0; ni < 4; ++ni) {
                int r = ni * 16 + (lane & 15);
                int off = r * 128 + (((kh * 4 + (lane >> 4)) ^ (r & 7)) * 16);
                bS[ni] = *(const bf16x8*)(smWs + off);
                bD[ni] = *(const bf16x8*)(smWd + off);
            }
#pragma unroll
            for (int mi = 0; mi < 2; ++mi)
#pragma unroll
                for (int ni = 0; ni < 4; ++ni) {
                    accS[mi][ni] = __builtin_amdgcn_mfma_f32_16x16x32_bf16(aS[mi], bS[ni], accS[mi][ni], 0, 0, 0);
                    accD[mi][ni] = __builtin_amdgcn_mfma_f32_16x16x32_bf16(aS[mi], bD[ni], accD[mi][ni], 0, 0, 0);
                }
        }
        __syncthreads();
    }

#pragma unroll
    for (int mi = 0; mi < 2; ++mi)
#pragma unroll
        for (int ni = 0; ni < 4; ++ni) {
            int j = ni * 16 + (lane & 15);
            if (j >= CDIM) continue;
            f32x4 cs = accS[mi][ni], cd = accD[mi][ni];
#pragma unroll
            for (int r = 0; r < 4; ++r) {
                int n = n0 + wv * 32 + mi * 16 + (lane >> 4) * 4 + r;
                zs[(size_t)n * CDIM + j] = cs[r];
                zd[(size_t)n * CDIM + j] = cd[r];
            }
        }
}

// ---------------- layer 3: gather over 40 classes + bias + log_softmax ----------------
__global__ __launch_bounds__(256) void k_l3(const float* __restrict__ zs,
                                            const float* __restrict__ zd,
                                            const int* __restrict__ rptr,
                                            const int* __restrict__ nbr_r,
                                            const float* __restrict__ w_r,
                                            const int* __restrict__ cptr,
                                            const int* __restrict__ nbr_c,
                                            const float* __restrict__ w_c,
                                            const float* __restrict__ bs,
                                            const float* __restrict__ bd,
                                            float* __restrict__ out, int N) {
    int wv = threadIdx.x >> 6, lane = threadIdx.x & 63;
    int n = blockIdx.x * 4 + wv;
    if (n >= N) return;
    float val = 0.0f;
    if (lane < CDIM) val = 0.5f * bs[lane] + 0.5f * bd[lane];
    int s = rptr[n], t = rptr[n + 1];
    for (int p = s; p < t; ++p) {
        int c = nbr_r[p];
        float wt = w_r[p];
        if (lane < CDIM) val += 0.5f * wt * zs[(size_t)c * CDIM + lane];
    }
    s = cptr[n];
    t = cptr[n + 1];
    for (int p = s; p < t; ++p) {
        int r = nbr_c[p];
        float wt = w_c[p];
        if (lane < CDIM) val += 0.5f * wt * zd[(size_t)r * CDIM + lane];
    }
    float m = (lane < CDIM) ? val : -INFINITY;
    for (int off = 32; off; off >>= 1) m = fmaxf(m, __shfl_xor(m, off));
    float ex = (lane < CDIM) ? expf(val - m) : 0.0f;
    for (int off = 32; off; off >>= 1) ex += __shfl_xor(ex, off);
    float lse = logf(ex);
    if (lane < CDIM) out[(size_t)n * CDIM + lane] = val - m - lse;
}

extern "C" void kernel_launch(void* const* d_in, const int* in_sizes, int n_in,
                              void* d_out, int out_size, void* d_ws, size_t ws_size,
                              hipStream_t stream) {
    const int N = in_sizes[0] / FDIM;
    const int E = in_sizes[1] / 2;
    const int NP = cdiv(N, NPAD_TO) * NPAD_TO;

    const float* x = (const float*)d_in[0];
    const int* ei = (const int*)d_in[1];
    const int* row = ei;
    const int* col = ei + E;
    const float* ws1 = (const float*)d_in[2];
    const float* bs1 = (const float*)d_in[3];
    const float* wd1 = (const float*)d_in[4];
    const float* bd1 = (const float*)d_in[5];
    const float* ws2 = (const float*)d_in[6];
    const float* bs2 = (const float*)d_in[7];
    const float* wd2 = (const float*)d_in[8];
    const float* bd2 = (const float*)d_in[9];
    const float* ws3 = (const float*)d_in[10];
    const float* bs3 = (const float*)d_in[11];
    const float* wd3 = (const float*)d_in[12];
    const float* bd3 = (const float*)d_in[13];
    float* out = (float*)d_out;

    // ---- workspace carve ----
    char* base = (char*)d_ws;
    float* inv_out = (float*)base;  base += sizeof(float) * N;
    float* inv_in = (float*)base;   base += sizeof(float) * N;
    int* cnt_r = (int*)base;        base += sizeof(int) * N;
    int* cnt_c = (int*)base;        base += sizeof(int) * N;
    int* fr = (int*)base;           base += sizeof(int) * N;
    int* fc = (int*)base;           base += sizeof(int) * N;
    int* rptr = (int*)base;         base += sizeof(int) * (N + 1);
    int* cptr = (int*)base;         base += sizeof(int) * (N + 1);
    int* bsum = (int*)base;         base += sizeof(int) * 256;
    int* nbr_r = (int*)base;        base += sizeof(int) * E;
    float* w_r = (float*)base;      base += sizeof(float) * E;
    int* nbr_c = (int*)base;        base += sizeof(int) * E;
    float* w_c = (float*)base;      base += sizeof(float) * E;
    base = (char*)(((size_t)base + 255) & ~(size_t)255);
    ushort* xb = (ushort*)base;     base += sizeof(ushort) * (size_t)N * FDIM;
    base = (char*)(((size_t)base + 255) & ~(size_t)255);
    ushort* hb = (ushort*)base;     base += sizeof(ushort) * (size_t)NP * FDIM;
    ushort* aggb = (ushort*)base;   base += sizeof(ushort) * (size_t)NP * FDIM;
    ushort* aggtb = (ushort*)base;  base += sizeof(ushort) * (size_t)NP * FDIM;
    ushort* wbuf = (ushort*)base;   base += sizeof(ushort) * (4 * 65536 + 2 * 16384);
    // layer-3 outputs alias the (then-free) agg buffers
    float* zs = (float*)aggb;
    float* zd = (float*)aggtb;

    ushort* w1s = wbuf;
    ushort* w1d = wbuf + 65536;
    ushort* w2s = wbuf + 2 * 65536;
    ushort* w2d = wbuf + 3 * 65536;
    ushort* w3s = wbuf + 4 * 65536;
    ushort* w3d = wbuf + 4 * 65536 + 16384;

    const int nb = cdiv(N, 256);

    // ---- build normalization + CSR/CSC ----
    hipMemsetAsync(cnt_r, 0, sizeof(int) * 4 * (size_t)N, stream);
    k_count<<<cdiv(E, 256), 256, 0, stream>>>(row, col, cnt_r, cnt_c, E);
    k_inv<<<cdiv(2 * N, 256), 256, 0, stream>>>(cnt_r, inv_out, 2 * N);
    k_scan1<<<nb, 256, 0, stream>>>(cnt_r, rptr, bsum, N);
    k_scan2<<<1, 256, 0, stream>>>(bsum, nb);
    k_scan3<<<nb, 256, 0, stream>>>(rptr, bsum, N, E);
    k_scan1<<<nb, 256, 0, stream>>>(cnt_c, cptr, bsum, N);
    k_scan2<<<1, 256, 0, stream>>>(bsum, nb);
    k_scan3<<<nb, 256, 0, stream>>>(cptr, bsum, N, E);
    k_fill<<<cdiv(E, 256), 256, 0, stream>>>(row, col, inv_out, inv_in, rptr, cptr,
                                             fr, fc, nbr_r, w_r, nbr_c, w_c, E);

    // ---- casts ----
    k_castx<<<cdiv(N * FDIM / 4, 256), 256, 0, stream>>>(x, xb, N * FDIM / 4);
    k_castw<<<cdiv(4 * 65536 + 2 * 16384, 256), 256, 0, stream>>>(ws1, wd1, ws2, wd2, ws3, wd3, wbuf);

    dim3 ggrid(cdiv(N, 4), 2);
    dim3 ggemm(NP / 128, FDIM / 64);
    dim3 ggemm3(NP / 128, 1);

    // layer 1
    k_gather_bf<<<ggrid, 256, 0, stream>>>(xb, rptr, nbr_r, w_r, cptr, nbr_c, w_c, aggb, aggtb, N);
    k_gemm12<<<ggemm, 256, 0, stream>>>(aggb, aggtb, w1s, w1d, bs1, bd1, hb);

    // layer 2
    k_gather_bf<<<ggrid, 256, 0, stream>>>(hb, rptr, nbr_r, w_r, cptr, nbr_c, w_c, aggb, aggtb, N);
    k_gemm12<<<ggemm, 256, 0, stream>>>(aggb, aggtb, w2s, w2d, bs2, bd2, hb);

    // layer 3
    k_gemm3<<<ggemm3, 256, 0, stream>>>(hb, w3s, w3d, zs, zd);
    k_l3<<<cdiv(N, 4), 256, 0, stream>>>(zs, zd, rptr, nbr_r, w_r, cptr, nbr_c, w_c,
                                         bs3, bd3, out, N);
}

// Round 4
// 543.417 us; speedup vs baseline: 21.9064x; 1.2543x over previous
//
#include <hip/hip_runtime.h>
#include <math.h>

#define FDIM 256
#define CDIM 40
#define ZPAD 64
#define NPAD_TO 128

typedef __attribute__((ext_vector_type(8))) __bf16 bf16x8;
typedef __attribute__((ext_vector_type(4))) float f32x4;

static inline int cdiv(int a, int b) { return (a + b - 1) / b; }

__device__ __forceinline__ float b2f(ushort u) { return __uint_as_float(((unsigned)u) << 16); }
__device__ __forceinline__ ushort f2bf(float f) {
    unsigned u = __float_as_uint(f);
    unsigned r = (u + 0x7FFFu + ((u >> 16) & 1u)) >> 16;
    return (ushort)r;
}

__device__ __forceinline__ void gl_lds16(const void* gsrc, void* ldst) {
    __builtin_amdgcn_global_load_lds((const __attribute__((address_space(1))) unsigned*)gsrc,
                                     (__attribute__((address_space(3))) unsigned*)ldst, 16, 0, 0);
}

// ---------------- degree counting / CSR-CSC build ----------------
__global__ __launch_bounds__(256) void k_count(const int* __restrict__ row,
                                               const int* __restrict__ col,
                                               int* __restrict__ cnt_r,
                                               int* __restrict__ cnt_c, int E) {
    int e = blockIdx.x * 256 + threadIdx.x;
    if (e < E) {
        atomicAdd(&cnt_r[row[e]], 1);
        atomicAdd(&cnt_c[col[e]], 1);
    }
}

__global__ __launch_bounds__(256) void k_inv(const int* __restrict__ cnt,
                                             float* __restrict__ inv, int n) {
    int i = blockIdx.x * 256 + threadIdx.x;
    if (i < n) {
        int c = cnt[i];
        inv[i] = c > 0 ? rsqrtf((float)c) : 0.0f;
    }
}

__global__ __launch_bounds__(256) void k_scan1(const int* __restrict__ cnt,
                                               int* __restrict__ ptr,
                                               int* __restrict__ bsum, int n) {
    __shared__ int s[256];
    int t = threadIdx.x;
    int i = blockIdx.x * 256 + t;
    int v = (i < n) ? cnt[i] : 0;
    s[t] = v;
    __syncthreads();
    for (int off = 1; off < 256; off <<= 1) {
        int u = (t >= off) ? s[t - off] : 0;
        __syncthreads();
        s[t] += u;
        __syncthreads();
    }
    if (i < n) ptr[i] = s[t] - v;
    if (t == 255) bsum[blockIdx.x] = s[255];
}

__global__ __launch_bounds__(256) void k_scan2(int* __restrict__ bsum, int nb) {
    __shared__ int s[256];
    int t = threadIdx.x;
    int v = (t < nb) ? bsum[t] : 0;
    s[t] = v;
    __syncthreads();
    for (int off = 1; off < 256; off <<= 1) {
        int u = (t >= off) ? s[t - off] : 0;
        __syncthreads();
        s[t] += u;
        __syncthreads();
    }
    if (t < nb) bsum[t] = s[t] - v;
}

__global__ __launch_bounds__(256) void k_scan3(int* __restrict__ ptr,
                                               const int* __restrict__ bsum,
                                               int n, int total) {
    int i = blockIdx.x * 256 + threadIdx.x;
    if (i < n) ptr[i] += bsum[blockIdx.x];
    if (blockIdx.x == 0 && threadIdx.x == 0) ptr[n] = total;
}

__global__ __launch_bounds__(256) void k_fill(const int* __restrict__ row,
                                              const int* __restrict__ col,
                                              const float* __restrict__ inv_out,
                                              const float* __restrict__ inv_in,
                                              const int* __restrict__ rptr,
                                              const int* __restrict__ cptr,
                                              int* __restrict__ fr, int* __restrict__ fc,
                                              int* __restrict__ nbr_r, float* __restrict__ w_r,
                                              int* __restrict__ nbr_c, float* __restrict__ w_c,
                                              int E) {
    int e = blockIdx.x * 256 + threadIdx.x;
    if (e >= E) return;
    int r = row[e], c = col[e];
    float wv = inv_out[r] * inv_in[c];
    int p = rptr[r] + atomicAdd(&fr[r], 1);
    nbr_r[p] = c;
    w_r[p] = wv;
    int q = cptr[c] + atomicAdd(&fc[c], 1);
    nbr_c[q] = r;
    w_c[q] = wv;
}

// ---------------- casts ----------------
__global__ __launch_bounds__(256) void k_castx(const float* __restrict__ x,
                                               ushort* __restrict__ xb, int n4) {
    int i = blockIdx.x * 256 + threadIdx.x;
    if (i < n4) {
        float4 v = ((const float4*)x)[i];
        ushort4 o;
        o.x = f2bf(v.x); o.y = f2bf(v.y); o.z = f2bf(v.z); o.w = f2bf(v.w);
        ((ushort4*)xb)[i] = o;
    }
}

// wbuf layout (bf16): w1s[256*256] w1d[256*256] w2s[256*256] w2d[256*256] w3s[64*256] w3d[64*256]
__global__ __launch_bounds__(256) void k_castw(const float* __restrict__ s1, const float* __restrict__ d1,
                                               const float* __restrict__ s2, const float* __restrict__ d2,
                                               const float* __restrict__ s3, const float* __restrict__ d3,
                                               ushort* __restrict__ wb) {
    int i = blockIdx.x * 256 + threadIdx.x;
    const int BIG = 256 * 256;
    const int SM = 64 * 256;
    if (i >= 4 * BIG + 2 * SM) return;
    float v;
    if (i < BIG) v = s1[i];
    else if (i < 2 * BIG) v = d1[i - BIG];
    else if (i < 3 * BIG) v = s2[i - 2 * BIG];
    else if (i < 4 * BIG) v = d2[i - 3 * BIG];
    else {
        int o = i - 4 * BIG;
        const float* src = (o < SM) ? s3 : d3;
        o = (o < SM) ? o : o - SM;
        int r = o >> 8;
        v = (r < CDIM) ? src[(r << 8) + (o & 255)] : 0.0f;
    }
    wb[i] = f2bf(v);
}

// ---------------- bf16 gather with register-prefetched neighbor lists ----------------
__global__ __launch_bounds__(256) void k_gather_bf(const ushort* __restrict__ hb,
                                                   const int* __restrict__ rptr,
                                                   const int* __restrict__ nbr_r,
                                                   const float* __restrict__ w_r,
                                                   const int* __restrict__ cptr,
                                                   const int* __restrict__ nbr_c,
                                                   const float* __restrict__ w_c,
                                                   ushort* __restrict__ agg,
                                                   ushort* __restrict__ aggt, int N) {
    int wv = threadIdx.x >> 6, lane = threadIdx.x & 63;
    int n = blockIdx.x * 4 + wv;
    if (n >= N) return;
    const int* ptr;
    const int* nbr;
    const float* w;
    ushort* out;
    if (blockIdx.y == 0) { ptr = rptr; nbr = nbr_r; w = w_r; out = agg; }
    else                 { ptr = cptr; nbr = nbr_c; w = w_c; out = aggt; }
    int s = ptr[n], t = ptr[n + 1];
    float a0 = 0.f, a1 = 0.f, a2 = 0.f, a3 = 0.f;
    for (int base = s; base < t; base += 64) {
        int cnt = t - base;
        if (cnt > 64) cnt = 64;
        int idx = 0;
        float ww = 0.f;
        if (lane < cnt) {
            idx = nbr[base + lane];
            ww = w[base + lane];
        }
        int i = 0;
        for (; i + 1 < cnt; i += 2) {
            int c0 = __shfl(idx, i, 64), c1 = __shfl(idx, i + 1, 64);
            float w0 = __shfl(ww, i, 64), w1 = __shfl(ww, i + 1, 64);
            ushort4 v0 = ((const ushort4*)(hb + (size_t)c0 * FDIM))[lane];
            ushort4 v1 = ((const ushort4*)(hb + (size_t)c1 * FDIM))[lane];
            a0 += w0 * b2f(v0.x) + w1 * b2f(v1.x);
            a1 += w0 * b2f(v0.y) + w1 * b2f(v1.y);
            a2 += w0 * b2f(v0.z) + w1 * b2f(v1.z);
            a3 += w0 * b2f(v0.w) + w1 * b2f(v1.w);
        }
        if (i < cnt) {
            int c0 = __shfl(idx, i, 64);
            float w0 = __shfl(ww, i, 64);
            ushort4 v0 = ((const ushort4*)(hb + (size_t)c0 * FDIM))[lane];
            a0 += w0 * b2f(v0.x);
            a1 += w0 * b2f(v0.y);
            a2 += w0 * b2f(v0.z);
            a3 += w0 * b2f(v0.w);
        }
    }
    ushort4 o;
    o.x = f2bf(a0); o.y = f2bf(a1); o.z = f2bf(a2); o.w = f2bf(a3);
    ((ushort4*)(out + (size_t)n * FDIM))[lane] = o;
}

// ---------------- MFMA dual GEMM, layers 1-2 (unchanged) ----------------
__global__ __launch_bounds__(256) void k_gemm12(const ushort* __restrict__ Ab,
                                                const ushort* __restrict__ Atb,
                                                const ushort* __restrict__ Wsb,
                                                const ushort* __restrict__ Wdb,
                                                const float* __restrict__ bs,
                                                const float* __restrict__ bd,
                                                ushort* __restrict__ outH) {
    __shared__ char smA[16384];
    __shared__ char smAt[16384];
    __shared__ char smWs[8192];
    __shared__ char smWd[8192];

    const int tid = threadIdx.x;
    const int wv = tid >> 6, lane = tid & 63;
    const int n0 = blockIdx.x * 128;
    const int j0 = blockIdx.y * 64;

    const char* Abase = (const char*)Ab;
    const char* Atbase = (const char*)Atb;
    const char* Wsbase = (const char*)Wsb;
    const char* Wdbase = (const char*)Wdb;

    f32x4 accS[2][4] = {};
    f32x4 accD[2][4] = {};

    for (int k0 = 0; k0 < FDIM; k0 += 64) {
#pragma unroll
        for (int it = 0; it < 4; ++it) {
            int si = (wv * 4 + it) * 64 + lane;
            int r = si >> 3, sl = si & 7;
            int gs = sl ^ (r & 7);
            size_t goff = (size_t)(n0 + r) * (FDIM * 2) + k0 * 2 + gs * 16;
            gl_lds16(Abase + goff, smA + si * 16);
            gl_lds16(Atbase + goff, smAt + si * 16);
        }
#pragma unroll
        for (int it = 0; it < 2; ++it) {
            int si = (wv * 2 + it) * 64 + lane;
            int r = si >> 3, sl = si & 7;
            int gs = sl ^ (r & 7);
            size_t goff = (size_t)(j0 + r) * (FDIM * 2) + k0 * 2 + gs * 16;
            gl_lds16(Wsbase + goff, smWs + si * 16);
            gl_lds16(Wdbase + goff, smWd + si * 16);
        }
        __syncthreads();
#pragma unroll
        for (int kh = 0; kh < 2; ++kh) {
            bf16x8 aS[2], aT[2], bS[4], bD[4];
#pragma unroll
            for (int mi = 0; mi < 2; ++mi) {
                int r = wv * 32 + mi * 16 + (lane & 15);
                int off = r * 128 + (((kh * 4 + (lane >> 4)) ^ (r & 7)) * 16);
                aS[mi] = *(const bf16x8*)(smA + off);
                aT[mi] = *(const bf16x8*)(smAt + off);
            }
#pragma unroll
            for (int ni = 0; ni < 4; ++ni) {
                int r = ni * 16 + (lane & 15);
                int off = r * 128 + (((kh * 4 + (lane >> 4)) ^ (r & 7)) * 16);
                bS[ni] = *(const bf16x8*)(smWs + off);
                bD[ni] = *(const bf16x8*)(smWd + off);
            }
#pragma unroll
            for (int mi = 0; mi < 2; ++mi)
#pragma unroll
                for (int ni = 0; ni < 4; ++ni) {
                    accS[mi][ni] = __builtin_amdgcn_mfma_f32_16x16x32_bf16(aS[mi], bS[ni], accS[mi][ni], 0, 0, 0);
                    accD[mi][ni] = __builtin_amdgcn_mfma_f32_16x16x32_bf16(aT[mi], bD[ni], accD[mi][ni], 0, 0, 0);
                }
        }
        __syncthreads();
    }

#pragma unroll
    for (int mi = 0; mi < 2; ++mi)
#pragma unroll
        for (int ni = 0; ni < 4; ++ni) {
            int j = j0 + ni * 16 + (lane & 15);
            float bsv = bs[j], bdv = bd[j];
            f32x4 cs = accS[mi][ni], cd = accD[mi][ni];
#pragma unroll
            for (int r = 0; r < 4; ++r) {
                int n = n0 + wv * 32 + mi * 16 + (lane >> 4) * 4 + r;
                float v = 0.5f * (cs[r] + bsv) + 0.5f * (cd[r] + bdv);
                v = fmaxf(v, 0.0f);
                outH[(size_t)n * FDIM + j] = f2bf(v);
            }
        }
}

// ---------------- MFMA layer-3 GEMM: zs/zd as bf16 padded to 64 cols ----------------
__global__ __launch_bounds__(256) void k_gemm3(const ushort* __restrict__ Hb,
                                               const ushort* __restrict__ Wsb,
                                               const ushort* __restrict__ Wdb,
                                               ushort* __restrict__ zsb,
                                               ushort* __restrict__ zdb) {
    __shared__ char smA[16384];
    __shared__ char smWs[8192];
    __shared__ char smWd[8192];

    const int tid = threadIdx.x;
    const int wv = tid >> 6, lane = tid & 63;
    const int n0 = blockIdx.x * 128;

    const char* Abase = (const char*)Hb;
    const char* Wsbase = (const char*)Wsb;
    const char* Wdbase = (const char*)Wdb;

    f32x4 accS[2][4] = {};
    f32x4 accD[2][4] = {};

    for (int k0 = 0; k0 < FDIM; k0 += 64) {
#pragma unroll
        for (int it = 0; it < 4; ++it) {
            int si = (wv * 4 + it) * 64 + lane;
            int r = si >> 3, sl = si & 7;
            int gs = sl ^ (r & 7);
            size_t goff = (size_t)(n0 + r) * (FDIM * 2) + k0 * 2 + gs * 16;
            gl_lds16(Abase + goff, smA + si * 16);
        }
#pragma unroll
        for (int it = 0; it < 2; ++it) {
            int si = (wv * 2 + it) * 64 + lane;
            int r = si >> 3, sl = si & 7;
            int gs = sl ^ (r & 7);
            size_t goff = (size_t)r * (FDIM * 2) + k0 * 2 + gs * 16;
            gl_lds16(Wsbase + goff, smWs + si * 16);
            gl_lds16(Wdbase + goff, smWd + si * 16);
        }
        __syncthreads();
#pragma unroll
        for (int kh = 0; kh < 2; ++kh) {
            bf16x8 aS[2], bS[4], bD[4];
#pragma unroll
            for (int mi = 0; mi < 2; ++mi) {
                int r = wv * 32 + mi * 16 + (lane & 15);
                int off = r * 128 + (((kh * 4 + (lane >> 4)) ^ (r & 7)) * 16);
                aS[mi] = *(const bf16x8*)(smA + off);
            }
#pragma unroll
            for (int ni = 0; ni < 4; ++ni) {
                int r = ni * 16 + (lane & 15);
                int off = r * 128 + (((kh * 4 + (lane >> 4)) ^ (r & 7)) * 16);
                bS[ni] = *(const bf16x8*)(smWs + off);
                bD[ni] = *(const bf16x8*)(smWd + off);
            }
#pragma unroll
            for (int mi = 0; mi < 2; ++mi)
#pragma unroll
                for (int ni = 0; ni < 4; ++ni) {
                    accS[mi][ni] = __builtin_amdgcn_mfma_f32_16x16x32_bf16(aS[mi], bS[ni], accS[mi][ni], 0, 0, 0);
                    accD[mi][ni] = __builtin_amdgcn_mfma_f32_16x16x32_bf16(aS[mi], bD[ni], accD[mi][ni], 0, 0, 0);
                }
        }
        __syncthreads();
    }

#pragma unroll
    for (int mi = 0; mi < 2; ++mi)
#pragma unroll
        for (int ni = 0; ni < 4; ++ni) {
            int j = ni * 16 + (lane & 15);
            f32x4 cs = accS[mi][ni], cd = accD[mi][ni];
#pragma unroll
            for (int r = 0; r < 4; ++r) {
                int n = n0 + wv * 32 + mi * 16 + (lane >> 4) * 4 + r;
                zsb[(size_t)n * ZPAD + j] = f2bf(cs[r]);
                zdb[(size_t)n * ZPAD + j] = f2bf(cd[r]);
            }
        }
}

// ---------------- layer 3: gather over padded-64 bf16 z + bias + log_softmax ----------------
__global__ __launch_bounds__(256) void k_l3(const ushort* __restrict__ zsb,
                                            const ushort* __restrict__ zdb,
                                            const int* __restrict__ rptr,
                                            const int* __restrict__ nbr_r,
                                            const float* __restrict__ w_r,
                                            const int* __restrict__ cptr,
                                            const int* __restrict__ nbr_c,
                                            const float* __restrict__ w_c,
                                            const float* __restrict__ bs,
                                            const float* __restrict__ bd,
                                            float* __restrict__ out, int N) {
    int wv = threadIdx.x >> 6, lane = threadIdx.x & 63;
    int n = blockIdx.x * 4 + wv;
    if (n >= N) return;
    float val = 0.0f;

#pragma unroll
    for (int dir = 0; dir < 2; ++dir) {
        const int* ptr = dir == 0 ? rptr : cptr;
        const int* nbr = dir == 0 ? nbr_r : nbr_c;
        const float* w = dir == 0 ? w_r : w_c;
        const ushort* zb = dir == 0 ? zsb : zdb;
        int s = ptr[n], t = ptr[n + 1];
        for (int base = s; base < t; base += 64) {
            int cnt = t - base;
            if (cnt > 64) cnt = 64;
            int idx = 0;
            float ww = 0.f;
            if (lane < cnt) {
                idx = nbr[base + lane];
                ww = w[base + lane];
            }
            int i = 0;
            for (; i + 1 < cnt; i += 2) {
                int c0 = __shfl(idx, i, 64), c1 = __shfl(idx, i + 1, 64);
                float w0 = __shfl(ww, i, 64), w1 = __shfl(ww, i + 1, 64);
                float v0 = b2f(zb[(size_t)c0 * ZPAD + lane]);
                float v1 = b2f(zb[(size_t)c1 * ZPAD + lane]);
                val += 0.5f * (w0 * v0 + w1 * v1);
            }
            if (i < cnt) {
                int c0 = __shfl(idx, i, 64);
                float w0 = __shfl(ww, i, 64);
                val += 0.5f * w0 * b2f(zb[(size_t)c0 * ZPAD + lane]);
            }
        }
    }

    if (lane < CDIM) val += 0.5f * bs[lane] + 0.5f * bd[lane];
    float m = (lane < CDIM) ? val : -INFINITY;
    for (int off = 32; off; off >>= 1) m = fmaxf(m, __shfl_xor(m, off));
    float ex = (lane < CDIM) ? expf(val - m) : 0.0f;
    for (int off = 32; off; off >>= 1) ex += __shfl_xor(ex, off);
    float lse = logf(ex);
    if (lane < CDIM) out[(size_t)n * CDIM + lane] = val - m - lse;
}

extern "C" void kernel_launch(void* const* d_in, const int* in_sizes, int n_in,
                              void* d_out, int out_size, void* d_ws, size_t ws_size,
                              hipStream_t stream) {
    const int N = in_sizes[0] / FDIM;
    const int E = in_sizes[1] / 2;
    const int NP = cdiv(N, NPAD_TO) * NPAD_TO;

    const float* x = (const float*)d_in[0];
    const int* ei = (const int*)d_in[1];
    const int* row = ei;
    const int* col = ei + E;
    const float* ws1 = (const float*)d_in[2];
    const float* bs1 = (const float*)d_in[3];
    const float* wd1 = (const float*)d_in[4];
    const float* bd1 = (const float*)d_in[5];
    const float* ws2 = (const float*)d_in[6];
    const float* bs2 = (const float*)d_in[7];
    const float* wd2 = (const float*)d_in[8];
    const float* bd2 = (const float*)d_in[9];
    const float* ws3 = (const float*)d_in[10];
    const float* bs3 = (const float*)d_in[11];
    const float* wd3 = (const float*)d_in[12];
    const float* bd3 = (const float*)d_in[13];
    float* out = (float*)d_out;

    // ---- workspace carve ----
    char* base = (char*)d_ws;
    float* inv_out = (float*)base;  base += sizeof(float) * N;
    float* inv_in = (float*)base;   base += sizeof(float) * N;
    int* cnt_r = (int*)base;        base += sizeof(int) * N;
    int* cnt_c = (int*)base;        base += sizeof(int) * N;
    int* fr = (int*)base;           base += sizeof(int) * N;
    int* fc = (int*)base;           base += sizeof(int) * N;
    int* rptr = (int*)base;         base += sizeof(int) * (N + 1);
    int* cptr = (int*)base;         base += sizeof(int) * (N + 1);
    int* bsum = (int*)base;         base += sizeof(int) * 256;
    int* nbr_r = (int*)base;        base += sizeof(int) * E;
    float* w_r = (float*)base;      base += sizeof(float) * E;
    int* nbr_c = (int*)base;        base += sizeof(int) * E;
    float* w_c = (float*)base;      base += sizeof(float) * E;
    base = (char*)(((size_t)base + 255) & ~(size_t)255);
    ushort* xb = (ushort*)base;     base += sizeof(ushort) * (size_t)N * FDIM;
    base = (char*)(((size_t)base + 255) & ~(size_t)255);
    ushort* hb = (ushort*)base;     base += sizeof(ushort) * (size_t)NP * FDIM;
    ushort* aggb = (ushort*)base;   base += sizeof(ushort) * (size_t)NP * FDIM;
    ushort* aggtb = (ushort*)base;  base += sizeof(ushort) * (size_t)NP * FDIM;
    ushort* wbuf = (ushort*)base;   base += sizeof(ushort) * (4 * 65536 + 2 * 16384);
    // layer-3 z buffers alias the (then-free) agg buffers
    ushort* zsb = aggb;
    ushort* zdb = aggtb;

    ushort* w1s = wbuf;
    ushort* w1d = wbuf + 65536;
    ushort* w2s = wbuf + 2 * 65536;
    ushort* w2d = wbuf + 3 * 65536;
    ushort* w3s = wbuf + 4 * 65536;
    ushort* w3d = wbuf + 4 * 65536 + 16384;

    const int nb = cdiv(N, 256);

    // ---- build normalization + CSR/CSC ----
    hipMemsetAsync(cnt_r, 0, sizeof(int) * 4 * (size_t)N, stream);
    k_count<<<cdiv(E, 256), 256, 0, stream>>>(row, col, cnt_r, cnt_c, E);
    k_inv<<<cdiv(2 * N, 256), 256, 0, stream>>>(cnt_r, inv_out, 2 * N);
    k_scan1<<<nb, 256, 0, stream>>>(cnt_r, rptr, bsum, N);
    k_scan2<<<1, 256, 0, stream>>>(bsum, nb);
    k_scan3<<<nb, 256, 0, stream>>>(rptr, bsum, N, E);
    k_scan1<<<nb, 256, 0, stream>>>(cnt_c, cptr, bsum, N);
    k_scan2<<<1, 256, 0, stream>>>(bsum, nb);
    k_scan3<<<nb, 256, 0, stream>>>(cptr, bsum, N, E);
    k_fill<<<cdiv(E, 256), 256, 0, stream>>>(row, col, inv_out, inv_in, rptr, cptr,
                                             fr, fc, nbr_r, w_r, nbr_c, w_c, E);

    // ---- casts ----
    k_castx<<<cdiv(N * FDIM / 4, 256), 256, 0, stream>>>(x, xb, N * FDIM / 4);
    k_castw<<<cdiv(4 * 65536 + 2 * 16384, 256), 256, 0, stream>>>(ws1, wd1, ws2, wd2, ws3, wd3, wbuf);

    dim3 ggrid(cdiv(N, 4), 2);
    dim3 ggemm(NP / 128, FDIM / 64);
    dim3 ggemm3(NP / 128, 1);

    // layer 1
    k_gather_bf<<<ggrid, 256, 0, stream>>>(xb, rptr, nbr_r, w_r, cptr, nbr_c, w_c, aggb, aggtb, N);
    k_gemm12<<<ggemm, 256, 0, stream>>>(aggb, aggtb, w1s, w1d, bs1, bd1, hb);

    // layer 2
    k_gather_bf<<<ggrid, 256, 0, stream>>>(hb, rptr, nbr_r, w_r, cptr, nbr_c, w_c, aggb, aggtb, N);
    k_gemm12<<<ggemm, 256, 0, stream>>>(aggb, aggtb, w2s, w2d, bs2, bd2, hb);

    // layer 3
    k_gemm3<<<ggemm3, 256, 0, stream>>>(hb, w3s, w3d, zsb, zdb);
    k_l3<<<cdiv(N, 4), 256, 0, stream>>>(zsb, zdb, rptr, nbr_r, w_r, cptr, nbr_c, w_c,
                                         bs3, bd3, out, N);
}

// Round 5
// 525.584 us; speedup vs baseline: 22.6497x; 1.0339x over previous
//
#include <hip/hip_runtime.h>
#include <math.h>

#define FDIM 256
#define CDIM 40
#define ZPAD 64
#define NPAD_TO 128

typedef __attribute__((ext_vector_type(8))) __bf16 bf16x8;
typedef __attribute__((ext_vector_type(4))) float f32x4;
typedef __attribute__((ext_vector_type(8))) ushort u16x8;
typedef __attribute__((ext_vector_type(4))) ushort u16x4;

static inline int cdiv(int a, int b) { return (a + b - 1) / b; }

__device__ __forceinline__ float b2f(ushort u) { return __uint_as_float(((unsigned)u) << 16); }
__device__ __forceinline__ ushort f2bf(float f) {
    unsigned u = __float_as_uint(f);
    unsigned r = (u + 0x7FFFu + ((u >> 16) & 1u)) >> 16;
    return (ushort)r;
}

__device__ __forceinline__ void gl_lds16(const void* gsrc, void* ldst) {
    __builtin_amdgcn_global_load_lds((const __attribute__((address_space(1))) unsigned*)gsrc,
                                     (__attribute__((address_space(3))) unsigned*)ldst, 16, 0, 0);
}

// ---------------- degree counting / CSR-CSC build ----------------
__global__ __launch_bounds__(256) void k_count(const int* __restrict__ row,
                                               const int* __restrict__ col,
                                               int* __restrict__ cnt_r,
                                               int* __restrict__ cnt_c, int E) {
    int e = blockIdx.x * 256 + threadIdx.x;
    if (e < E) {
        atomicAdd(&cnt_r[row[e]], 1);
        atomicAdd(&cnt_c[col[e]], 1);
    }
}

__global__ __launch_bounds__(256) void k_inv(const int* __restrict__ cnt,
                                             float* __restrict__ inv, int n) {
    int i = blockIdx.x * 256 + threadIdx.x;
    if (i < n) {
        int c = cnt[i];
        inv[i] = c > 0 ? rsqrtf((float)c) : 0.0f;
    }
}

__global__ __launch_bounds__(256) void k_scan1(const int* __restrict__ cnt,
                                               int* __restrict__ ptr,
                                               int* __restrict__ bsum, int n) {
    __shared__ int s[256];
    int t = threadIdx.x;
    int i = blockIdx.x * 256 + t;
    int v = (i < n) ? cnt[i] : 0;
    s[t] = v;
    __syncthreads();
    for (int off = 1; off < 256; off <<= 1) {
        int u = (t >= off) ? s[t - off] : 0;
        __syncthreads();
        s[t] += u;
        __syncthreads();
    }
    if (i < n) ptr[i] = s[t] - v;
    if (t == 255) bsum[blockIdx.x] = s[255];
}

__global__ __launch_bounds__(256) void k_scan2(int* __restrict__ bsum, int nb) {
    __shared__ int s[256];
    int t = threadIdx.x;
    int v = (t < nb) ? bsum[t] : 0;
    s[t] = v;
    __syncthreads();
    for (int off = 1; off < 256; off <<= 1) {
        int u = (t >= off) ? s[t - off] : 0;
        __syncthreads();
        s[t] += u;
        __syncthreads();
    }
    if (t < nb) bsum[t] = s[t] - v;
}

__global__ __launch_bounds__(256) void k_scan3(int* __restrict__ ptr,
                                               const int* __restrict__ bsum,
                                               int n, int total) {
    int i = blockIdx.x * 256 + threadIdx.x;
    if (i < n) ptr[i] += bsum[blockIdx.x];
    if (blockIdx.x == 0 && threadIdx.x == 0) ptr[n] = total;
}

// packed (nbr, w_bits) pairs
__global__ __launch_bounds__(256) void k_fill(const int* __restrict__ row,
                                              const int* __restrict__ col,
                                              const float* __restrict__ inv_out,
                                              const float* __restrict__ inv_in,
                                              const int* __restrict__ rptr,
                                              const int* __restrict__ cptr,
                                              int* __restrict__ fr, int* __restrict__ fc,
                                              int2* __restrict__ pair_r,
                                              int2* __restrict__ pair_c,
                                              int E) {
    int e = blockIdx.x * 256 + threadIdx.x;
    if (e >= E) return;
    int r = row[e], c = col[e];
    float wv = inv_out[r] * inv_in[c];
    int wb = __float_as_int(wv);
    int p = rptr[r] + atomicAdd(&fr[r], 1);
    pair_r[p] = make_int2(c, wb);
    int q = cptr[c] + atomicAdd(&fc[c], 1);
    pair_c[q] = make_int2(r, wb);
}

// ---------------- casts ----------------
__global__ __launch_bounds__(256) void k_castx(const float* __restrict__ x,
                                               ushort* __restrict__ xb, int n4) {
    int i = blockIdx.x * 256 + threadIdx.x;
    if (i < n4) {
        float4 v = ((const float4*)x)[i];
        ushort4 o;
        o.x = f2bf(v.x); o.y = f2bf(v.y); o.z = f2bf(v.z); o.w = f2bf(v.w);
        ((ushort4*)xb)[i] = o;
    }
}

__global__ __launch_bounds__(256) void k_castw(const float* __restrict__ s1, const float* __restrict__ d1,
                                               const float* __restrict__ s2, const float* __restrict__ d2,
                                               const float* __restrict__ s3, const float* __restrict__ d3,
                                               ushort* __restrict__ wb) {
    int i = blockIdx.x * 256 + threadIdx.x;
    const int BIG = 256 * 256;
    const int SM = 64 * 256;
    if (i >= 4 * BIG + 2 * SM) return;
    float v;
    if (i < BIG) v = s1[i];
    else if (i < 2 * BIG) v = d1[i - BIG];
    else if (i < 3 * BIG) v = s2[i - 2 * BIG];
    else if (i < 4 * BIG) v = d2[i - 3 * BIG];
    else {
        int o = i - 4 * BIG;
        const float* src = (o < SM) ? s3 : d3;
        o = (o < SM) ? o : o - SM;
        int r = o >> 8;
        v = (r < CDIM) ? src[(r << 8) + (o & 255)] : 0.0f;
    }
    wb[i] = f2bf(v);
}

// ---------------- bf16 gather: half-wave 2-row split, ushort8 loads, 4 rows in flight ----------------
__global__ __launch_bounds__(256) void k_gather_bf(const ushort* __restrict__ hb,
                                                   const int* __restrict__ rptr,
                                                   const int2* __restrict__ pair_r,
                                                   const int* __restrict__ cptr,
                                                   const int2* __restrict__ pair_c,
                                                   ushort* __restrict__ agg,
                                                   ushort* __restrict__ aggt, int N) {
    int wv = threadIdx.x >> 6, lane = threadIdx.x & 63;
    int half = lane >> 5, l32 = lane & 31;
    int n = blockIdx.x * 4 + wv;
    if (n >= N) return;
    const int* ptr;
    const int2* pair;
    ushort* out;
    if (blockIdx.y == 0) { ptr = rptr; pair = pair_r; out = agg; }
    else                 { ptr = cptr; pair = pair_c; out = aggt; }
    int s = ptr[n], t = ptr[n + 1];
    float a[8] = {};
    for (int base = s; base < t; base += 64) {
        int cnt = t - base;
        if (cnt > 64) cnt = 64;
        int idx = 0;
        float ww = 0.f;
        if (lane < cnt) {
            int2 pk = pair[base + lane];
            idx = pk.x;
            ww = __int_as_float(pk.y);
        }
        for (int i = 0; i < cnt; i += 8) {
            int n0 = i + half, n1 = i + 2 + half, n2 = i + 4 + half, n3 = i + 6 + half;
            int c0 = __shfl(idx, n0, 64); float w0 = __shfl(ww, n0, 64);
            int c1 = __shfl(idx, n1, 64); float w1 = __shfl(ww, n1, 64);
            int c2 = __shfl(idx, n2, 64); float w2 = __shfl(ww, n2, 64);
            int c3 = __shfl(idx, n3, 64); float w3 = __shfl(ww, n3, 64);
            u16x8 v0 = ((const u16x8*)(hb + (size_t)c0 * FDIM))[l32];
            u16x8 v1 = ((const u16x8*)(hb + (size_t)c1 * FDIM))[l32];
            u16x8 v2 = ((const u16x8*)(hb + (size_t)c2 * FDIM))[l32];
            u16x8 v3 = ((const u16x8*)(hb + (size_t)c3 * FDIM))[l32];
#pragma unroll
            for (int j = 0; j < 8; ++j)
                a[j] += w0 * b2f(v0[j]) + w1 * b2f(v1[j]) + w2 * b2f(v2[j]) + w3 * b2f(v3[j]);
        }
    }
#pragma unroll
    for (int j = 0; j < 8; ++j) a[j] += __shfl_xor(a[j], 32, 64);
    if (half == 0) {
        u16x8 o;
#pragma unroll
        for (int j = 0; j < 8; ++j) o[j] = f2bf(a[j]);
        ((u16x8*)(out + (size_t)n * FDIM))[l32] = o;
    }
}

// ---------------- MFMA dual GEMM, layers 1-2 ----------------
__global__ __launch_bounds__(256) void k_gemm12(const ushort* __restrict__ Ab,
                                                const ushort* __restrict__ Atb,
                                                const ushort* __restrict__ Wsb,
                                                const ushort* __restrict__ Wdb,
                                                const float* __restrict__ bs,
                                                const float* __restrict__ bd,
                                                ushort* __restrict__ outH) {
    __shared__ char smA[16384];
    __shared__ char smAt[16384];
    __shared__ char smWs[8192];
    __shared__ char smWd[8192];

    const int tid = threadIdx.x;
    const int wv = tid >> 6, lane = tid & 63;
    const int n0 = blockIdx.x * 128;
    const int j0 = blockIdx.y * 64;

    const char* Abase = (const char*)Ab;
    const char* Atbase = (const char*)Atb;
    const char* Wsbase = (const char*)Wsb;
    const char* Wdbase = (const char*)Wdb;

    f32x4 accS[2][4] = {};
    f32x4 accD[2][4] = {};

    for (int k0 = 0; k0 < FDIM; k0 += 64) {
#pragma unroll
        for (int it = 0; it < 4; ++it) {
            int si = (wv * 4 + it) * 64 + lane;
            int r = si >> 3, sl = si & 7;
            int gs = sl ^ (r & 7);
            size_t goff = (size_t)(n0 + r) * (FDIM * 2) + k0 * 2 + gs * 16;
            gl_lds16(Abase + goff, smA + si * 16);
            gl_lds16(Atbase + goff, smAt + si * 16);
        }
#pragma unroll
        for (int it = 0; it < 2; ++it) {
            int si = (wv * 2 + it) * 64 + lane;
            int r = si >> 3, sl = si & 7;
            int gs = sl ^ (r & 7);
            size_t goff = (size_t)(j0 + r) * (FDIM * 2) + k0 * 2 + gs * 16;
            gl_lds16(Wsbase + goff, smWs + si * 16);
            gl_lds16(Wdbase + goff, smWd + si * 16);
        }
        __syncthreads();
#pragma unroll
        for (int kh = 0; kh < 2; ++kh) {
            bf16x8 aS[2], aT[2], bS[4], bD[4];
#pragma unroll
            for (int mi = 0; mi < 2; ++mi) {
                int r = wv * 32 + mi * 16 + (lane & 15);
                int off = r * 128 + (((kh * 4 + (lane >> 4)) ^ (r & 7)) * 16);
                aS[mi] = *(const bf16x8*)(smA + off);
                aT[mi] = *(const bf16x8*)(smAt + off);
            }
#pragma unroll
            for (int ni = 0; ni < 4; ++ni) {
                int r = ni * 16 + (lane & 15);
                int off = r * 128 + (((kh * 4 + (lane >> 4)) ^ (r & 7)) * 16);
                bS[ni] = *(const bf16x8*)(smWs + off);
                bD[ni] = *(const bf16x8*)(smWd + off);
            }
#pragma unroll
            for (int mi = 0; mi < 2; ++mi)
#pragma unroll
                for (int ni = 0; ni < 4; ++ni) {
                    accS[mi][ni] = __builtin_amdgcn_mfma_f32_16x16x32_bf16(aS[mi], bS[ni], accS[mi][ni], 0, 0, 0);
                    accD[mi][ni] = __builtin_amdgcn_mfma_f32_16x16x32_bf16(aT[mi], bD[ni], accD[mi][ni], 0, 0, 0);
                }
        }
        __syncthreads();
    }

#pragma unroll
    for (int mi = 0; mi < 2; ++mi)
#pragma unroll
        for (int ni = 0; ni < 4; ++ni) {
            int j = j0 + ni * 16 + (lane & 15);
            float bsv = bs[j], bdv = bd[j];
            f32x4 cs = accS[mi][ni], cd = accD[mi][ni];
#pragma unroll
            for (int r = 0; r < 4; ++r) {
                int n = n0 + wv * 32 + mi * 16 + (lane >> 4) * 4 + r;
                float v = 0.5f * (cs[r] + bsv) + 0.5f * (cd[r] + bdv);
                v = fmaxf(v, 0.0f);
                outH[(size_t)n * FDIM + j] = f2bf(v);
            }
        }
}

// ---------------- MFMA layer-3 GEMM: zs/zd as bf16 padded to 64 cols ----------------
__global__ __launch_bounds__(256) void k_gemm3(const ushort* __restrict__ Hb,
                                               const ushort* __restrict__ Wsb,
                                               const ushort* __restrict__ Wdb,
                                               ushort* __restrict__ zsb,
                                               ushort* __restrict__ zdb) {
    __shared__ char smA[16384];
    __shared__ char smWs[8192];
    __shared__ char smWd[8192];

    const int tid = threadIdx.x;
    const int wv = tid >> 6, lane = tid & 63;
    const int n0 = blockIdx.x * 128;

    const char* Abase = (const char*)Hb;
    const char* Wsbase = (const char*)Wsb;
    const char* Wdbase = (const char*)Wdb;

    f32x4 accS[2][4] = {};
    f32x4 accD[2][4] = {};

    for (int k0 = 0; k0 < FDIM; k0 += 64) {
#pragma unroll
        for (int it = 0; it < 4; ++it) {
            int si = (wv * 4 + it) * 64 + lane;
            int r = si >> 3, sl = si & 7;
            int gs = sl ^ (r & 7);
            size_t goff = (size_t)(n0 + r) * (FDIM * 2) + k0 * 2 + gs * 16;
            gl_lds16(Abase + goff, smA + si * 16);
        }
#pragma unroll
        for (int it = 0; it < 2; ++it) {
            int si = (wv * 2 + it) * 64 + lane;
            int r = si >> 3, sl = si & 7;
            int gs = sl ^ (r & 7);
            size_t goff = (size_t)r * (FDIM * 2) + k0 * 2 + gs * 16;
            gl_lds16(Wsbase + goff, smWs + si * 16);
            gl_lds16(Wdbase + goff, smWd + si * 16);
        }
        __syncthreads();
#pragma unroll
        for (int kh = 0; kh < 2; ++kh) {
            bf16x8 aS[2], bS[4], bD[4];
#pragma unroll
            for (int mi = 0; mi < 2; ++mi) {
                int r = wv * 32 + mi * 16 + (lane & 15);
                int off = r * 128 + (((kh * 4 + (lane >> 4)) ^ (r & 7)) * 16);
                aS[mi] = *(const bf16x8*)(smA + off);
            }
#pragma unroll
            for (int ni = 0; ni < 4; ++ni) {
                int r = ni * 16 + (lane & 15);
                int off = r * 128 + (((kh * 4 + (lane >> 4)) ^ (r & 7)) * 16);
                bS[ni] = *(const bf16x8*)(smWs + off);
                bD[ni] = *(const bf16x8*)(smWd + off);
            }
#pragma unroll
            for (int mi = 0; mi < 2; ++mi)
#pragma unroll
                for (int ni = 0; ni < 4; ++ni) {
                    accS[mi][ni] = __builtin_amdgcn_mfma_f32_16x16x32_bf16(aS[mi], bS[ni], accS[mi][ni], 0, 0, 0);
                    accD[mi][ni] = __builtin_amdgcn_mfma_f32_16x16x32_bf16(aS[mi], bD[ni], accD[mi][ni], 0, 0, 0);
                }
        }
        __syncthreads();
    }

#pragma unroll
    for (int mi = 0; mi < 2; ++mi)
#pragma unroll
        for (int ni = 0; ni < 4; ++ni) {
            int j = ni * 16 + (lane & 15);
            f32x4 cs = accS[mi][ni], cd = accD[mi][ni];
#pragma unroll
            for (int r = 0; r < 4; ++r) {
                int n = n0 + wv * 32 + mi * 16 + (lane >> 4) * 4 + r;
                zsb[(size_t)n * ZPAD + j] = f2bf(cs[r]);
                zdb[(size_t)n * ZPAD + j] = f2bf(cd[r]);
            }
        }
}

// ---------------- layer 3: 4-row-group gather over padded-64 bf16 z + log_softmax ----------------
__global__ __launch_bounds__(256) void k_l3(const ushort* __restrict__ zsb,
                                            const ushort* __restrict__ zdb,
                                            const int* __restrict__ rptr,
                                            const int2* __restrict__ pair_r,
                                            const int* __restrict__ cptr,
                                            const int2* __restrict__ pair_c,
                                            const float* __restrict__ bs,
                                            const float* __restrict__ bd,
                                            float* __restrict__ out, int N) {
    int wv = threadIdx.x >> 6, lane = threadIdx.x & 63;
    int grp = lane >> 4, sl = lane & 15;
    int n = blockIdx.x * 4 + wv;
    if (n >= N) return;
    float a[4] = {};

#pragma unroll
    for (int dir = 0; dir < 2; ++dir) {
        const int* ptr = dir == 0 ? rptr : cptr;
        const int2* pair = dir == 0 ? pair_r : pair_c;
        const ushort* zb = dir == 0 ? zsb : zdb;
        int s = ptr[n], t = ptr[n + 1];
        for (int base = s; base < t; base += 64) {
            int cnt = t - base;
            if (cnt > 64) cnt = 64;
            int idx = 0;
            float ww = 0.f;
            if (lane < cnt) {
                int2 pk = pair[base + lane];
                idx = pk.x;
                ww = __int_as_float(pk.y);
            }
            for (int i = 0; i < cnt; i += 8) {
                int n0 = i + grp, n1 = i + 4 + grp;
                int c0 = __shfl(idx, n0, 64); float w0 = __shfl(ww, n0, 64);
                int c1 = __shfl(idx, n1, 64); float w1 = __shfl(ww, n1, 64);
                u16x4 v0 = ((const u16x4*)(zb + (size_t)c0 * ZPAD))[sl];
                u16x4 v1 = ((const u16x4*)(zb + (size_t)c1 * ZPAD))[sl];
#pragma unroll
                for (int j = 0; j < 4; ++j)
                    a[j] += w0 * b2f(v0[j]) + w1 * b2f(v1[j]);
            }
        }
    }

#pragma unroll
    for (int j = 0; j < 4; ++j) {
        a[j] += __shfl_xor(a[j], 16, 64);
        a[j] += __shfl_xor(a[j], 32, 64);
        a[j] *= 0.5f;
    }
    // bias (classes 4*sl+j); only sl<10 are real classes
    float val[4];
#pragma unroll
    for (int j = 0; j < 4; ++j) {
        int c = 4 * sl + j;
        val[j] = (c < CDIM) ? a[j] + 0.5f * (bs[c] + bd[c]) : -INFINITY;
    }
    float m = fmaxf(fmaxf(val[0], val[1]), fmaxf(val[2], val[3]));
    for (int off = 1; off < 16; off <<= 1) m = fmaxf(m, __shfl_xor(m, off, 64));
    float ex = 0.f;
#pragma unroll
    for (int j = 0; j < 4; ++j) ex += (4 * sl + j < CDIM) ? expf(val[j] - m) : 0.f;
    for (int off = 1; off < 16; off <<= 1) ex += __shfl_xor(ex, off, 64);
    float lse = logf(ex);
    if (grp == 0 && sl < 10) {
        float4 o;
        o.x = val[0] - m - lse;
        o.y = val[1] - m - lse;
        o.z = val[2] - m - lse;
        o.w = val[3] - m - lse;
        ((float4*)(out + (size_t)n * CDIM))[sl] = o;
    }
}

extern "C" void kernel_launch(void* const* d_in, const int* in_sizes, int n_in,
                              void* d_out, int out_size, void* d_ws, size_t ws_size,
                              hipStream_t stream) {
    const int N = in_sizes[0] / FDIM;
    const int E = in_sizes[1] / 2;
    const int NP = cdiv(N, NPAD_TO) * NPAD_TO;

    const float* x = (const float*)d_in[0];
    const int* ei = (const int*)d_in[1];
    const int* row = ei;
    const int* col = ei + E;
    const float* ws1 = (const float*)d_in[2];
    const float* bs1 = (const float*)d_in[3];
    const float* wd1 = (const float*)d_in[4];
    const float* bd1 = (const float*)d_in[5];
    const float* ws2 = (const float*)d_in[6];
    const float* bs2 = (const float*)d_in[7];
    const float* wd2 = (const float*)d_in[8];
    const float* bd2 = (const float*)d_in[9];
    const float* ws3 = (const float*)d_in[10];
    const float* bs3 = (const float*)d_in[11];
    const float* wd3 = (const float*)d_in[12];
    const float* bd3 = (const float*)d_in[13];
    float* out = (float*)d_out;

    // ---- workspace carve ----
    char* base = (char*)d_ws;
    float* inv_out = (float*)base;  base += sizeof(float) * N;
    float* inv_in = (float*)base;   base += sizeof(float) * N;
    int* cnt_r = (int*)base;        base += sizeof(int) * N;
    int* cnt_c = (int*)base;        base += sizeof(int) * N;
    int* fr = (int*)base;           base += sizeof(int) * N;
    int* fc = (int*)base;           base += sizeof(int) * N;
    int* rptr = (int*)base;         base += sizeof(int) * (N + 1);
    int* cptr = (int*)base;         base += sizeof(int) * (N + 1);
    int* bsum = (int*)base;         base += sizeof(int) * 256;
    base = (char*)(((size_t)base + 15) & ~(size_t)15);
    int2* pair_r = (int2*)base;     base += sizeof(int2) * E;
    int2* pair_c = (int2*)base;     base += sizeof(int2) * E;
    base = (char*)(((size_t)base + 255) & ~(size_t)255);
    ushort* xb = (ushort*)base;     base += sizeof(ushort) * (size_t)N * FDIM;
    base = (char*)(((size_t)base + 255) & ~(size_t)255);
    ushort* hb = (ushort*)base;     base += sizeof(ushort) * (size_t)NP * FDIM;
    ushort* aggb = (ushort*)base;   base += sizeof(ushort) * (size_t)NP * FDIM;
    ushort* aggtb = (ushort*)base;  base += sizeof(ushort) * (size_t)NP * FDIM;
    ushort* wbuf = (ushort*)base;   base += sizeof(ushort) * (4 * 65536 + 2 * 16384);
    ushort* zsb = aggb;
    ushort* zdb = aggtb;

    ushort* w1s = wbuf;
    ushort* w1d = wbuf + 65536;
    ushort* w2s = wbuf + 2 * 65536;
    ushort* w2d = wbuf + 3 * 65536;
    ushort* w3s = wbuf + 4 * 65536;
    ushort* w3d = wbuf + 4 * 65536 + 16384;

    const int nb = cdiv(N, 256);

    // ---- build normalization + CSR/CSC ----
    hipMemsetAsync(cnt_r, 0, sizeof(int) * 4 * (size_t)N, stream);
    k_count<<<cdiv(E, 256), 256, 0, stream>>>(row, col, cnt_r, cnt_c, E);
    k_inv<<<cdiv(2 * N, 256), 256, 0, stream>>>(cnt_r, inv_out, 2 * N);
    k_scan1<<<nb, 256, 0, stream>>>(cnt_r, rptr, bsum, N);
    k_scan2<<<1, 256, 0, stream>>>(bsum, nb);
    k_scan3<<<nb, 256, 0, stream>>>(rptr, bsum, N, E);
    k_scan1<<<nb, 256, 0, stream>>>(cnt_c, cptr, bsum, N);
    k_scan2<<<1, 256, 0, stream>>>(bsum, nb);
    k_scan3<<<nb, 256, 0, stream>>>(cptr, bsum, N, E);
    k_fill<<<cdiv(E, 256), 256, 0, stream>>>(row, col, inv_out, inv_in, rptr, cptr,
                                             fr, fc, pair_r, pair_c, E);

    // ---- casts ----
    k_castx<<<cdiv(N * FDIM / 4, 256), 256, 0, stream>>>(x, xb, N * FDIM / 4);
    k_castw<<<cdiv(4 * 65536 + 2 * 16384, 256), 256, 0, stream>>>(ws1, wd1, ws2, wd2, ws3, wd3, wbuf);

    dim3 ggrid(cdiv(N, 4), 2);
    dim3 ggemm(NP / 128, FDIM / 64);
    dim3 ggemm3(NP / 128, 1);

    // layer 1
    k_gather_bf<<<ggrid, 256, 0, stream>>>(xb, rptr, pair_r, cptr, pair_c, aggb, aggtb, N);
    k_gemm12<<<ggemm, 256, 0, stream>>>(aggb, aggtb, w1s, w1d, bs1, bd1, hb);

    // layer 2
    k_gather_bf<<<ggrid, 256, 0, stream>>>(hb, rptr, pair_r, cptr, pair_c, aggb, aggtb, N);
    k_gemm12<<<ggemm, 256, 0, stream>>>(aggb, aggtb, w2s, w2d, bs2, bd2, hb);

    // layer 3
    k_gemm3<<<ggemm3, 256, 0, stream>>>(hb, w3s, w3d, zsb, zdb);
    k_l3<<<cdiv(N, 4), 256, 0, stream>>>(zsb, zdb, rptr, pair_r, cptr, pair_c,
                                         bs3, bd3, out, N);
}

// Round 6
// 509.548 us; speedup vs baseline: 23.3625x; 1.0315x over previous
//
#include <hip/hip_runtime.h>
#include <math.h>

#define FDIM 256
#define CDIM 40
#define ZPAD 64
#define NPAD_TO 128

typedef __attribute__((ext_vector_type(8))) __bf16 bf16x8;
typedef __attribute__((ext_vector_type(4))) float f32x4;
typedef __attribute__((ext_vector_type(8))) ushort u16x8;
typedef __attribute__((ext_vector_type(4))) ushort u16x4;

static inline int cdiv(int a, int b) { return (a + b - 1) / b; }

__device__ __forceinline__ float b2f(ushort u) { return __uint_as_float(((unsigned)u) << 16); }
__device__ __forceinline__ ushort f2bf(float f) {
    unsigned u = __float_as_uint(f);
    unsigned r = (u + 0x7FFFu + ((u >> 16) & 1u)) >> 16;
    return (ushort)r;
}

__device__ __forceinline__ void gl_lds16(const void* gsrc, void* ldst) {
    __builtin_amdgcn_global_load_lds((const __attribute__((address_space(1))) unsigned*)gsrc,
                                     (__attribute__((address_space(3))) unsigned*)ldst, 16, 0, 0);
}

// ---------------- degree counting / CSR-CSC build ----------------
__global__ __launch_bounds__(256) void k_count(const int* __restrict__ row,
                                               const int* __restrict__ col,
                                               int* __restrict__ cnt_r,
                                               int* __restrict__ cnt_c, int E) {
    int e = blockIdx.x * 256 + threadIdx.x;
    if (e < E) {
        atomicAdd(&cnt_r[row[e]], 1);
        atomicAdd(&cnt_c[col[e]], 1);
    }
}

// fused r/c scan via blockIdx.y
__global__ __launch_bounds__(256) void k_scan1(const int* __restrict__ cnt_r,
                                               const int* __restrict__ cnt_c,
                                               int* __restrict__ rptr,
                                               int* __restrict__ cptr,
                                               int* __restrict__ bsum, int n) {
    const int* cnt = blockIdx.y ? cnt_c : cnt_r;
    int* ptr = blockIdx.y ? cptr : rptr;
    __shared__ int s[256];
    int t = threadIdx.x;
    int i = blockIdx.x * 256 + t;
    int v = (i < n) ? cnt[i] : 0;
    s[t] = v;
    __syncthreads();
    for (int off = 1; off < 256; off <<= 1) {
        int u = (t >= off) ? s[t - off] : 0;
        __syncthreads();
        s[t] += u;
        __syncthreads();
    }
    if (i < n) ptr[i] = s[t] - v;
    if (t == 255) bsum[blockIdx.y * 256 + blockIdx.x] = s[255];
}

__global__ __launch_bounds__(256) void k_scan2(int* __restrict__ bsum, int nb) {
    int* b = bsum + blockIdx.x * 256;
    __shared__ int s[256];
    int t = threadIdx.x;
    int v = (t < nb) ? b[t] : 0;
    s[t] = v;
    __syncthreads();
    for (int off = 1; off < 256; off <<= 1) {
        int u = (t >= off) ? s[t - off] : 0;
        __syncthreads();
        s[t] += u;
        __syncthreads();
    }
    if (t < nb) b[t] = s[t] - v;
}

__global__ __launch_bounds__(256) void k_scan3(int* __restrict__ rptr,
                                               int* __restrict__ cptr,
                                               const int* __restrict__ bsum,
                                               int n, int total) {
    int* ptr = blockIdx.y ? cptr : rptr;
    int i = blockIdx.x * 256 + threadIdx.x;
    if (i < n) ptr[i] += bsum[blockIdx.y * 256 + blockIdx.x];
    if (blockIdx.x == 0 && threadIdx.x == 0) ptr[n] = total;
}

// packed (nbr, w_bits) pairs; rsqrt computed inline from counts
__global__ __launch_bounds__(256) void k_fill(const int* __restrict__ row,
                                              const int* __restrict__ col,
                                              const int* __restrict__ cnt_r,
                                              const int* __restrict__ cnt_c,
                                              const int* __restrict__ rptr,
                                              const int* __restrict__ cptr,
                                              int* __restrict__ fr, int* __restrict__ fc,
                                              int2* __restrict__ pair_r,
                                              int2* __restrict__ pair_c,
                                              int E) {
    int e = blockIdx.x * 256 + threadIdx.x;
    if (e >= E) return;
    int r = row[e], c = col[e];
    // endpoints of an existing edge always have degree >= 1
    float wv = rsqrtf((float)cnt_r[r]) * rsqrtf((float)cnt_c[c]);
    int wb = __float_as_int(wv);
    int p = rptr[r] + atomicAdd(&fr[r], 1);
    pair_r[p] = make_int2(c, wb);
    int q = cptr[c] + atomicAdd(&fc[c], 1);
    pair_c[q] = make_int2(r, wb);
}

// ---------------- merged casts: x (float4->ushort4) then weights ----------------
__global__ __launch_bounds__(256) void k_cast(const float* __restrict__ x, int n4,
                                              const float* __restrict__ s1, const float* __restrict__ d1,
                                              const float* __restrict__ s2, const float* __restrict__ d2,
                                              const float* __restrict__ s3, const float* __restrict__ d3,
                                              ushort* __restrict__ xb,
                                              ushort* __restrict__ wb) {
    int i = blockIdx.x * 256 + threadIdx.x;
    if (i < n4) {
        float4 v = ((const float4*)x)[i];
        ushort4 o;
        o.x = f2bf(v.x); o.y = f2bf(v.y); o.z = f2bf(v.z); o.w = f2bf(v.w);
        ((ushort4*)xb)[i] = o;
        return;
    }
    int o = i - n4;
    const int BIG = 256 * 256;
    const int SM = 64 * 256;
    if (o >= 4 * BIG + 2 * SM) return;
    float v;
    if (o < BIG) v = s1[o];
    else if (o < 2 * BIG) v = d1[o - BIG];
    else if (o < 3 * BIG) v = s2[o - 2 * BIG];
    else if (o < 4 * BIG) v = d2[o - 3 * BIG];
    else {
        int oo = o - 4 * BIG;
        const float* src = (oo < SM) ? s3 : d3;
        oo = (oo < SM) ? oo : oo - SM;
        int r = oo >> 8;
        v = (r < CDIM) ? src[(r << 8) + (oo & 255)] : 0.0f;
    }
    wb[o] = f2bf(v);
}

// ---------------- bf16 gather: half-wave 2-row split, ushort8 loads ----------------
__global__ __launch_bounds__(256) void k_gather_bf(const ushort* __restrict__ hb,
                                                   const int* __restrict__ rptr,
                                                   const int2* __restrict__ pair_r,
                                                   const int* __restrict__ cptr,
                                                   const int2* __restrict__ pair_c,
                                                   ushort* __restrict__ agg,
                                                   ushort* __restrict__ aggt, int N) {
    int wv = threadIdx.x >> 6, lane = threadIdx.x & 63;
    int half = lane >> 5, l32 = lane & 31;
    int n = blockIdx.x * 4 + wv;
    if (n >= N) return;
    const int* ptr;
    const int2* pair;
    ushort* out;
    if (blockIdx.y == 0) { ptr = rptr; pair = pair_r; out = agg; }
    else                 { ptr = cptr; pair = pair_c; out = aggt; }
    int s = ptr[n], t = ptr[n + 1];
    float a[8] = {};
    for (int base = s; base < t; base += 64) {
        int cnt = t - base;
        if (cnt > 64) cnt = 64;
        int idx = 0;
        float ww = 0.f;
        if (lane < cnt) {
            int2 pk = pair[base + lane];
            idx = pk.x;
            ww = __int_as_float(pk.y);
        }
        for (int i = 0; i < cnt; i += 8) {
            int n0 = i + half, n1 = i + 2 + half, n2 = i + 4 + half, n3 = i + 6 + half;
            int c0 = __shfl(idx, n0, 64); float w0 = __shfl(ww, n0, 64);
            int c1 = __shfl(idx, n1, 64); float w1 = __shfl(ww, n1, 64);
            int c2 = __shfl(idx, n2, 64); float w2 = __shfl(ww, n2, 64);
            int c3 = __shfl(idx, n3, 64); float w3 = __shfl(ww, n3, 64);
            u16x8 v0 = ((const u16x8*)(hb + (size_t)c0 * FDIM))[l32];
            u16x8 v1 = ((const u16x8*)(hb + (size_t)c1 * FDIM))[l32];
            u16x8 v2 = ((const u16x8*)(hb + (size_t)c2 * FDIM))[l32];
            u16x8 v3 = ((const u16x8*)(hb + (size_t)c3 * FDIM))[l32];
#pragma unroll
            for (int j = 0; j < 8; ++j)
                a[j] += w0 * b2f(v0[j]) + w1 * b2f(v1[j]) + w2 * b2f(v2[j]) + w3 * b2f(v3[j]);
        }
    }
#pragma unroll
    for (int j = 0; j < 8; ++j) a[j] += __shfl_xor(a[j], 32, 64);
    if (half == 0) {
        u16x8 o;
#pragma unroll
        for (int j = 0; j < 8; ++j) o[j] = f2bf(a[j]);
        ((u16x8*)(out + (size_t)n * FDIM))[l32] = o;
    }
}

// ---------------- MFMA dual GEMM layers 1-2: BM=64 x BN=128, grid (NP/64, 2) ----------------
// A-stripe staged once per j-block: A re-read 2x (was 4x).
__global__ __launch_bounds__(256) void k_gemm12(const ushort* __restrict__ Ab,
                                                const ushort* __restrict__ Atb,
                                                const ushort* __restrict__ Wsb,
                                                const ushort* __restrict__ Wdb,
                                                const float* __restrict__ bs,
                                                const float* __restrict__ bd,
                                                ushort* __restrict__ outH) {
    __shared__ char smA[8192];
    __shared__ char smAt[8192];
    __shared__ char smWs[16384];
    __shared__ char smWd[16384];

    const int tid = threadIdx.x;
    const int wv = tid >> 6, lane = tid & 63;
    const int n0 = blockIdx.x * 64;
    const int j0 = blockIdx.y * 128;

    const char* Abase = (const char*)Ab;
    const char* Atbase = (const char*)Atb;
    const char* Wsbase = (const char*)Wsb;
    const char* Wdbase = (const char*)Wdb;

    f32x4 accS[8] = {};
    f32x4 accD[8] = {};

    for (int k0 = 0; k0 < FDIM; k0 += 64) {
        // stage A/At: 512 slots of 16B each
#pragma unroll
        for (int it = 0; it < 2; ++it) {
            int si = it * 256 + tid;
            int r = si >> 3, sl = si & 7;
            int gs = sl ^ (r & 7);
            size_t goff = (size_t)(n0 + r) * (FDIM * 2) + k0 * 2 + gs * 16;
            gl_lds16(Abase + goff, smA + si * 16);
            gl_lds16(Atbase + goff, smAt + si * 16);
        }
        // stage Ws/Wd: 1024 slots each
#pragma unroll
        for (int it = 0; it < 4; ++it) {
            int si = it * 256 + tid;
            int r = si >> 3, sl = si & 7;
            int gs = sl ^ (r & 7);
            size_t goff = (size_t)(j0 + r) * (FDIM * 2) + k0 * 2 + gs * 16;
            gl_lds16(Wsbase + goff, smWs + si * 16);
            gl_lds16(Wdbase + goff, smWd + si * 16);
        }
        __syncthreads();
#pragma unroll
        for (int kh = 0; kh < 2; ++kh) {
            int rA = wv * 16 + (lane & 15);
            int sA = (kh * 4 + (lane >> 4)) ^ (rA & 7);
            bf16x8 aS = *(const bf16x8*)(smA + rA * 128 + sA * 16);
            bf16x8 aT = *(const bf16x8*)(smAt + rA * 128 + sA * 16);
#pragma unroll
            for (int ni = 0; ni < 8; ++ni) {
                int rB = ni * 16 + (lane & 15);
                int sB = (kh * 4 + (lane >> 4)) ^ (rB & 7);
                bf16x8 bSv = *(const bf16x8*)(smWs + rB * 128 + sB * 16);
                bf16x8 bDv = *(const bf16x8*)(smWd + rB * 128 + sB * 16);
                accS[ni] = __builtin_amdgcn_mfma_f32_16x16x32_bf16(aS, bSv, accS[ni], 0, 0, 0);
                accD[ni] = __builtin_amdgcn_mfma_f32_16x16x32_bf16(aT, bDv, accD[ni], 0, 0, 0);
            }
        }
        __syncthreads();
    }

#pragma unroll
    for (int ni = 0; ni < 8; ++ni) {
        int j = j0 + ni * 16 + (lane & 15);
        float bsv = bs[j], bdv = bd[j];
#pragma unroll
        for (int r = 0; r < 4; ++r) {
            int n = n0 + wv * 16 + (lane >> 4) * 4 + r;
            float v = 0.5f * (accS[ni][r] + bsv) + 0.5f * (accD[ni][r] + bdv);
            v = fmaxf(v, 0.0f);
            outH[(size_t)n * FDIM + j] = f2bf(v);
        }
    }
}

// ---------------- MFMA layer-3 GEMM: zs/zd as bf16 padded to 64 cols ----------------
__global__ __launch_bounds__(256) void k_gemm3(const ushort* __restrict__ Hb,
                                               const ushort* __restrict__ Wsb,
                                               const ushort* __restrict__ Wdb,
                                               ushort* __restrict__ zsb,
                                               ushort* __restrict__ zdb) {
    __shared__ char smA[16384];
    __shared__ char smWs[8192];
    __shared__ char smWd[8192];

    const int tid = threadIdx.x;
    const int wv = tid >> 6, lane = tid & 63;
    const int n0 = blockIdx.x * 128;

    const char* Abase = (const char*)Hb;
    const char* Wsbase = (const char*)Wsb;
    const char* Wdbase = (const char*)Wdb;

    f32x4 accS[2][4] = {};
    f32x4 accD[2][4] = {};

    for (int k0 = 0; k0 < FDIM; k0 += 64) {
#pragma unroll
        for (int it = 0; it < 4; ++it) {
            int si = (wv * 4 + it) * 64 + lane;
            int r = si >> 3, sl = si & 7;
            int gs = sl ^ (r & 7);
            size_t goff = (size_t)(n0 + r) * (FDIM * 2) + k0 * 2 + gs * 16;
            gl_lds16(Abase + goff, smA + si * 16);
        }
#pragma unroll
        for (int it = 0; it < 2; ++it) {
            int si = (wv * 2 + it) * 64 + lane;
            int r = si >> 3, sl = si & 7;
            int gs = sl ^ (r & 7);
            size_t goff = (size_t)r * (FDIM * 2) + k0 * 2 + gs * 16;
            gl_lds16(Wsbase + goff, smWs + si * 16);
            gl_lds16(Wdbase + goff, smWd + si * 16);
        }
        __syncthreads();
#pragma unroll
        for (int kh = 0; kh < 2; ++kh) {
            bf16x8 aS[2], bS[4], bD[4];
#pragma unroll
            for (int mi = 0; mi < 2; ++mi) {
                int r = wv * 32 + mi * 16 + (lane & 15);
                int off = r * 128 + (((kh * 4 + (lane >> 4)) ^ (r & 7)) * 16);
                aS[mi] = *(const bf16x8*)(smA + off);
            }
#pragma unroll
            for (int ni = 0; ni < 4; ++ni) {
                int r = ni * 16 + (lane & 15);
                int off = r * 128 + (((kh * 4 + (lane >> 4)) ^ (r & 7)) * 16);
                bS[ni] = *(const bf16x8*)(smWs + off);
                bD[ni] = *(const bf16x8*)(smWd + off);
            }
#pragma unroll
            for (int mi = 0; mi < 2; ++mi)
#pragma unroll
                for (int ni = 0; ni < 4; ++ni) {
                    accS[mi][ni] = __builtin_amdgcn_mfma_f32_16x16x32_bf16(aS[mi], bS[ni], accS[mi][ni], 0, 0, 0);
                    accD[mi][ni] = __builtin_amdgcn_mfma_f32_16x16x32_bf16(aS[mi], bD[ni], accD[mi][ni], 0, 0, 0);
                }
        }
        __syncthreads();
    }

#pragma unroll
    for (int mi = 0; mi < 2; ++mi)
#pragma unroll
        for (int ni = 0; ni < 4; ++ni) {
            int j = ni * 16 + (lane & 15);
            f32x4 cs = accS[mi][ni], cd = accD[mi][ni];
#pragma unroll
            for (int r = 0; r < 4; ++r) {
                int n = n0 + wv * 32 + mi * 16 + (lane >> 4) * 4 + r;
                zsb[(size_t)n * ZPAD + j] = f2bf(cs[r]);
                zdb[(size_t)n * ZPAD + j] = f2bf(cd[r]);
            }
        }
}

// ---------------- layer 3: 4-row-group gather over padded-64 bf16 z + log_softmax ----------------
__global__ __launch_bounds__(256) void k_l3(const ushort* __restrict__ zsb,
                                            const ushort* __restrict__ zdb,
                                            const int* __restrict__ rptr,
                                            const int2* __restrict__ pair_r,
                                            const int* __restrict__ cptr,
                                            const int2* __restrict__ pair_c,
                                            const float* __restrict__ bs,
                                            const float* __restrict__ bd,
                                            float* __restrict__ out, int N) {
    int wv = threadIdx.x >> 6, lane = threadIdx.x & 63;
    int grp = lane >> 4, sl = lane & 15;
    int n = blockIdx.x * 4 + wv;
    if (n >= N) return;
    float a[4] = {};

#pragma unroll
    for (int dir = 0; dir < 2; ++dir) {
        const int* ptr = dir == 0 ? rptr : cptr;
        const int2* pair = dir == 0 ? pair_r : pair_c;
        const ushort* zb = dir == 0 ? zsb : zdb;
        int s = ptr[n], t = ptr[n + 1];
        for (int base = s; base < t; base += 64) {
            int cnt = t - base;
            if (cnt > 64) cnt = 64;
            int idx = 0;
            float ww = 0.f;
            if (lane < cnt) {
                int2 pk = pair[base + lane];
                idx = pk.x;
                ww = __int_as_float(pk.y);
            }
            for (int i = 0; i < cnt; i += 8) {
                int n0 = i + grp, n1 = i + 4 + grp;
                int c0 = __shfl(idx, n0, 64); float w0 = __shfl(ww, n0, 64);
                int c1 = __shfl(idx, n1, 64); float w1 = __shfl(ww, n1, 64);
                u16x4 v0 = ((const u16x4*)(zb + (size_t)c0 * ZPAD))[sl];
                u16x4 v1 = ((const u16x4*)(zb + (size_t)c1 * ZPAD))[sl];
#pragma unroll
                for (int j = 0; j < 4; ++j)
                    a[j] += w0 * b2f(v0[j]) + w1 * b2f(v1[j]);
            }
        }
    }

#pragma unroll
    for (int j = 0; j < 4; ++j) {
        a[j] += __shfl_xor(a[j], 16, 64);
        a[j] += __shfl_xor(a[j], 32, 64);
        a[j] *= 0.5f;
    }
    float val[4];
#pragma unroll
    for (int j = 0; j < 4; ++j) {
        int c = 4 * sl + j;
        val[j] = (c < CDIM) ? a[j] + 0.5f * (bs[c] + bd[c]) : -INFINITY;
    }
    float m = fmaxf(fmaxf(val[0], val[1]), fmaxf(val[2], val[3]));
    for (int off = 1; off < 16; off <<= 1) m = fmaxf(m, __shfl_xor(m, off, 64));
    float ex = 0.f;
#pragma unroll
    for (int j = 0; j < 4; ++j) ex += (4 * sl + j < CDIM) ? expf(val[j] - m) : 0.f;
    for (int off = 1; off < 16; off <<= 1) ex += __shfl_xor(ex, off, 64);
    float lse = logf(ex);
    if (grp == 0 && sl < 10) {
        float4 o;
        o.x = val[0] - m - lse;
        o.y = val[1] - m - lse;
        o.z = val[2] - m - lse;
        o.w = val[3] - m - lse;
        ((float4*)(out + (size_t)n * CDIM))[sl] = o;
    }
}

extern "C" void kernel_launch(void* const* d_in, const int* in_sizes, int n_in,
                              void* d_out, int out_size, void* d_ws, size_t ws_size,
                              hipStream_t stream) {
    const int N = in_sizes[0] / FDIM;
    const int E = in_sizes[1] / 2;
    const int NP = cdiv(N, NPAD_TO) * NPAD_TO;

    const float* x = (const float*)d_in[0];
    const int* ei = (const int*)d_in[1];
    const int* row = ei;
    const int* col = ei + E;
    const float* ws1 = (const float*)d_in[2];
    const float* bs1 = (const float*)d_in[3];
    const float* wd1 = (const float*)d_in[4];
    const float* bd1 = (const float*)d_in[5];
    const float* ws2 = (const float*)d_in[6];
    const float* bs2 = (const float*)d_in[7];
    const float* wd2 = (const float*)d_in[8];
    const float* bd2 = (const float*)d_in[9];
    const float* ws3 = (const float*)d_in[10];
    const float* bs3 = (const float*)d_in[11];
    const float* wd3 = (const float*)d_in[12];
    const float* bd3 = (const float*)d_in[13];
    float* out = (float*)d_out;

    // ---- workspace carve ----
    char* base = (char*)d_ws;
    int* cnt_r = (int*)base;        base += sizeof(int) * N;
    int* cnt_c = (int*)base;        base += sizeof(int) * N;
    int* fr = (int*)base;           base += sizeof(int) * N;
    int* fc = (int*)base;           base += sizeof(int) * N;
    int* rptr = (int*)base;         base += sizeof(int) * (N + 1);
    int* cptr = (int*)base;         base += sizeof(int) * (N + 1);
    int* bsum = (int*)base;         base += sizeof(int) * 512;
    base = (char*)(((size_t)base + 15) & ~(size_t)15);
    int2* pair_r = (int2*)base;     base += sizeof(int2) * E;
    int2* pair_c = (int2*)base;     base += sizeof(int2) * E;
    base = (char*)(((size_t)base + 255) & ~(size_t)255);
    ushort* xb = (ushort*)base;     base += sizeof(ushort) * (size_t)NP * FDIM;
    ushort* hb = (ushort*)base;     base += sizeof(ushort) * (size_t)NP * FDIM;
    ushort* aggb = (ushort*)base;   base += sizeof(ushort) * (size_t)NP * FDIM;
    ushort* aggtb = (ushort*)base;  base += sizeof(ushort) * (size_t)NP * FDIM;
    ushort* wbuf = (ushort*)base;   base += sizeof(ushort) * (4 * 65536 + 2 * 16384);
    ushort* zsb = aggb;
    ushort* zdb = aggtb;

    ushort* w1s = wbuf;
    ushort* w1d = wbuf + 65536;
    ushort* w2s = wbuf + 2 * 65536;
    ushort* w2d = wbuf + 3 * 65536;
    ushort* w3s = wbuf + 4 * 65536;
    ushort* w3d = wbuf + 4 * 65536 + 16384;

    const int nb = cdiv(N, 256);
    const int n4 = N * FDIM / 4;
    const int wn = 4 * 65536 + 2 * 16384;

    // ---- build normalization + CSR/CSC (fused scans) ----
    hipMemsetAsync(cnt_r, 0, sizeof(int) * 4 * (size_t)N, stream);
    k_count<<<cdiv(E, 256), 256, 0, stream>>>(row, col, cnt_r, cnt_c, E);
    k_scan1<<<dim3(nb, 2), 256, 0, stream>>>(cnt_r, cnt_c, rptr, cptr, bsum, N);
    k_scan2<<<2, 256, 0, stream>>>(bsum, nb);
    k_scan3<<<dim3(nb, 2), 256, 0, stream>>>(rptr, cptr, bsum, N, E);
    k_fill<<<cdiv(E, 256), 256, 0, stream>>>(row, col, cnt_r, cnt_c, rptr, cptr,
                                             fr, fc, pair_r, pair_c, E);

    // ---- casts (merged) ----
    k_cast<<<cdiv(n4 + wn, 256), 256, 0, stream>>>(x, n4, ws1, wd1, ws2, wd2, ws3, wd3, xb, wbuf);

    dim3 ggrid(cdiv(N, 4), 2);
    dim3 ggemm(NP / 64, 2);
    dim3 ggemm3(NP / 128, 1);

    // layer 1
    k_gather_bf<<<ggrid, 256, 0, stream>>>(xb, rptr, pair_r, cptr, pair_c, aggb, aggtb, N);
    k_gemm12<<<ggemm, 256, 0, stream>>>(aggb, aggtb, w1s, w1d, bs1, bd1, hb);

    // layer 2
    k_gather_bf<<<ggrid, 256, 0, stream>>>(hb, rptr, pair_r, cptr, pair_c, aggb, aggtb, N);
    k_gemm12<<<ggemm, 256, 0, stream>>>(aggb, aggtb, w2s, w2d, bs2, bd2, hb);

    // layer 3
    k_gemm3<<<ggemm3, 256, 0, stream>>>(hb, w3s, w3d, zsb, zdb);
    k_l3<<<cdiv(N, 4), 256, 0, stream>>>(zsb, zdb, rptr, pair_r, cptr, pair_c,
                                         bs3, bd3, out, N);
}